// Round 1
// baseline (971.325 us; speedup 1.0000x reference)
//
#include <hip/hip_runtime.h>
#include <math.h>

#define E_N    1536
#define ORBN   54
#define NATOMS 64
#define M_DIM  3456          // 54*64
#define NP     256
#define NQ     384
#define HRSZ   2916          // 54*54

#define W_FP 0.0002f
#define W_FQ 0.0001f
#define W_FO 0.00015f
#define W_FR (1.0f - W_FP - W_FQ - W_FO)

// ---------------- block reduction helper ----------------
__device__ __forceinline__ float blockSum(float v, float* sm) {
    v += __shfl_down(v, 32); v += __shfl_down(v, 16); v += __shfl_down(v, 8);
    v += __shfl_down(v, 4);  v += __shfl_down(v, 2);  v += __shfl_down(v, 1);
    __syncthreads();                       // safe reuse of sm
    if ((threadIdx.x & 63) == 0) sm[threadIdx.x >> 6] = v;
    __syncthreads();
    float r = 0.0f;
    if (threadIdx.x == 0) {
        int nw = blockDim.x >> 6;
        for (int i = 0; i < nw; ++i) r += sm[i];
    }
    return r;
}

// ---------------- phase factors per edge ----------------
__global__ void k_phase(const float* __restrict__ edge_vec,
                        const float* __restrict__ lat,
                        const float* __restrict__ apos,
                        const float* __restrict__ kpt,
                        const int* __restrict__ esrc,
                        const int* __restrict__ edst,
                        float* __restrict__ ph_re, float* __restrict__ ph_im) {
    int e = blockIdx.x * blockDim.x + threadIdx.x;
    if (e >= E_N) return;
    // A = lattice^T  (A[i][j] = lat[j*3+i]);  cell_inv = inv(A)
    float a00 = lat[0], a01 = lat[3], a02 = lat[6];
    float a10 = lat[1], a11 = lat[4], a12 = lat[7];
    float a20 = lat[2], a21 = lat[5], a22 = lat[8];
    float c00 = a11*a22 - a12*a21;
    float c01 = a12*a20 - a10*a22;
    float c02 = a10*a21 - a11*a20;
    float det = a00*c00 + a01*c01 + a02*c02;
    float id  = 1.0f / det;
    float i00 = c00*id;
    float i01 = (a02*a21 - a01*a22)*id;
    float i02 = (a01*a12 - a02*a11)*id;
    float i10 = c01*id;
    float i11 = (a00*a22 - a02*a20)*id;
    float i12 = (a02*a10 - a00*a12)*id;
    float i20 = c02*id;
    float i21 = (a01*a20 - a00*a21)*id;
    float i22 = (a00*a11 - a01*a10)*id;
    int s = esrc[e], d = edst[e];
    float r0 = edge_vec[e*3+0] - (apos[d*3+0] - apos[s*3+0]);
    float r1 = edge_vec[e*3+1] - (apos[d*3+1] - apos[s*3+1]);
    float r2 = edge_vec[e*3+2] - (apos[d*3+2] - apos[s*3+2]);
    float t0 = roundf(i00*r0 + i01*r1 + i02*r2);
    float t1 = roundf(i10*r0 + i11*r1 + i12*r2);
    float t2 = roundf(i20*r0 + i21*r1 + i22*r2);
    float ph = t0*kpt[0] + t1*kpt[1] + t2*kpt[2];
    float ang = 6.28318530717958647692f * ph;
    ph_re[e] = cosf(ang);
    ph_im[e] = sinf(ang);
}

// ---------------- reduction: n1 numerator, overlap^2, mask sum ----------------
__global__ __launch_bounds__(256) void k_red1(const float4* __restrict__ Hg,
                                              const float4* __restrict__ Hp,
                                              const float4* __restrict__ ov,
                                              const float4* __restrict__ mk,
                                              float* __restrict__ acc) {
    const int N4 = E_N*HRSZ/4;     // 1119744
    int stride = gridDim.x * blockDim.x;
    float s0 = 0, s1 = 0, s2 = 0;
    for (int i = blockIdx.x*blockDim.x + threadIdx.x; i < N4; i += stride) {
        float4 hg = Hg[i], hp = Hp[i], o = ov[i], m = mk[i];
        s0 += (hp.x-hg.x)*o.x + (hp.y-hg.y)*o.y + (hp.z-hg.z)*o.z + (hp.w-hg.w)*o.w;
        s1 += o.x*o.x + o.y*o.y + o.z*o.z + o.w*o.w;
        s2 += m.x + m.y + m.z + m.w;
    }
    __shared__ float sm[8];
    float r0 = blockSum(s0, sm);
    float r1 = blockSum(s1, sm);
    float r2 = blockSum(s2, sm);
    if (threadIdx.x == 0) {
        atomicAdd(&acc[0], r0);
        atomicAdd(&acc[1], r1);
        atomicAdd(&acc[2], r2);
    }
}

// ---------------- BP = hk_d @ P^T,  BQ = hk_d @ Q^T  (block-sparse) ----------------
// grid: 64 atoms x 10 col-tiles (4 for P, 6 for Q); block 256 = (rg 16 rowgroups x cg 16 colgroups), 4x4 per thread
__global__ __launch_bounds__(256) void k_bp(
        const float* __restrict__ hr_gt, const float* __restrict__ hr_pred,
        const float* __restrict__ P_re, const float* __restrict__ P_im,
        const float* __restrict__ Q_re, const float* __restrict__ Q_im,
        const int* __restrict__ esrc, const int* __restrict__ edst,
        const float* __restrict__ ph_re, const float* __restrict__ ph_im,
        float* __restrict__ BPre, float* __restrict__ BPim,
        float* __restrict__ BQre, float* __restrict__ BQim) {
    __shared__ float4 sH[54*16];   // hr_d transposed: [j][rowgroup] swizzled
    __shared__ float4 sR[54*16];   // P_re panel:      [j][colgroup] swizzled
    __shared__ float4 sI[54*16];   // P_im panel
    __shared__ int elist[E_N];
    __shared__ int ecnt;

    int tid = threadIdx.x;
    int a   = blockIdx.x / 10;
    int t   = blockIdx.x - a*10;
    const float* Are; const float* Aim; float* Ore; float* Oim; int NC; int col0;
    if (t < 4) { Are = P_re; Aim = P_im; Ore = BPre; Oim = BPim; NC = NP; col0 = t*64; }
    else       { Are = Q_re; Aim = Q_im; Ore = BQre; Oim = BQim; NC = NQ; col0 = (t-4)*64; }

    if (tid == 0) ecnt = 0;
    __syncthreads();
    for (int k = tid; k < E_N; k += 256)
        if (esrc[k] == a) { int p = atomicAdd(&ecnt, 1); elist[p] = k; }
    __syncthreads();
    int ne = ecnt;

    int rg = tid & 15;      // row group (rows 4rg..4rg+3)
    int cg = tid >> 4;      // col group (cols 4cg..4cg+3)
    float accre[4][4] = {{0}}, accim[4][4] = {{0}};

    for (int n = 0; n < ne; ++n) {
        int e = elist[n];
        int dst = edst[e];
        float phr = ph_re[e], phi = ph_im[e];
        __syncthreads();   // previous compute done before restaging
        {
            const float* hg = hr_gt  + (size_t)e*HRSZ;
            const float* hp = hr_pred + (size_t)e*HRSZ;
            for (int k = tid; k < 64*54; k += 256) {
                int i = k / 54, j = k - i*54;
                float v = (i < 54) ? (hp[i*54+j] - hg[i*54+j]) : 0.0f;
                int g = i >> 2;
                ((float*)sH)[(j*16 + (g ^ (j & 15)))*4 + (i & 3)] = v;
            }
            int rowb = dst*54;
            for (int k = tid; k < 64*54; k += 256) {
                int c = k / 54, j = k - c*54;
                size_t gi = (size_t)(col0 + c)*M_DIM + rowb + j;
                int g = c >> 2;
                int idx = (j*16 + (g ^ (j & 15)))*4 + (c & 3);
                ((float*)sR)[idx] = Are[gi];
                ((float*)sI)[idx] = Aim[gi];
            }
        }
        __syncthreads();

        float tre[4][4] = {{0}}, tim[4][4] = {{0}};
        #pragma unroll 3
        for (int j = 0; j < 54; ++j) {
            float4 h  = sH[j*16 + (rg ^ (j & 15))];
            float4 pr = sR[j*16 + (cg ^ (j & 15))];
            float4 pi = sI[j*16 + (cg ^ (j & 15))];
            float hh[4]  = {h.x, h.y, h.z, h.w};
            float prr[4] = {pr.x, pr.y, pr.z, pr.w};
            float pii[4] = {pi.x, pi.y, pi.z, pi.w};
            #pragma unroll
            for (int u = 0; u < 4; ++u)
                #pragma unroll
                for (int v = 0; v < 4; ++v) {
                    tre[u][v] += hh[u]*prr[v];
                    tim[u][v] += hh[u]*pii[v];
                }
        }
        #pragma unroll
        for (int u = 0; u < 4; ++u)
            #pragma unroll
            for (int v = 0; v < 4; ++v) {
                accre[u][v] += phr*tre[u][v] - phi*tim[u][v];
                accim[u][v] += phr*tim[u][v] + phi*tre[u][v];
            }
    }

    int m0 = a*54;
    #pragma unroll
    for (int u = 0; u < 4; ++u) {
        int i = rg*4 + u;
        if (i < 54) {
            size_t row = (size_t)(m0 + i)*NC + col0 + cg*4;
            *(float4*)(Ore + row) = make_float4(accre[u][0], accre[u][1], accre[u][2], accre[u][3]);
            *(float4*)(Oim + row) = make_float4(accim[u][0], accim[u][1], accim[u][2], accim[u][3]);
        }
    }
}

// ---------------- complex GEMMs: dP = conj(P)@BP, dQ = conj(Q)@BQ, dPQ = conj(P)@BQ ----------------
// 64x64 tile, K-split 4 (chunks of 864), fp32 atomicAdd epilogue. 304 blocks total.
__global__ __launch_bounds__(256) void k_gemm(
        const float* __restrict__ P_re, const float* __restrict__ P_im,
        const float* __restrict__ Q_re, const float* __restrict__ Q_im,
        const float* __restrict__ BPre, const float* __restrict__ BPim,
        const float* __restrict__ BQre, const float* __restrict__ BQim,
        float* __restrict__ dPre, float* __restrict__ dPim,
        float* __restrict__ dQre, float* __restrict__ dQim,
        float* __restrict__ dPQre, float* __restrict__ dPQim) {
    __shared__ float sAre[16*68], sAim[16*68], sBre[16*68], sBim[16*68];
    int tid = threadIdx.x;
    int bid = blockIdx.x;
    const float *Are, *Aim, *Bre, *Bim; float *Cre, *Cim;
    int rt, ct, ks, NC;
    if (bid < 64) {
        Are = P_re; Aim = P_im; Bre = BPre; Bim = BPim; Cre = dPre; Cim = dPim; NC = NP;
        rt = bid & 3; ct = (bid >> 2) & 3; ks = bid >> 4;
    } else if (bid < 208) {
        int loc = bid - 64;
        Are = Q_re; Aim = Q_im; Bre = BQre; Bim = BQim; Cre = dQre; Cim = dQim; NC = NQ;
        rt = loc % 6; ct = (loc / 6) % 6; ks = loc / 36;
    } else {
        int loc = bid - 208;
        Are = P_re; Aim = P_im; Bre = BQre; Bim = BQim; Cre = dPQre; Cim = dPQim; NC = NQ;
        rt = loc & 3; ct = (loc >> 2) % 6; ks = loc / 24;
    }
    int r0 = rt*64, c0 = ct*64, k0 = ks*864;

    int ap = tid >> 2, aq = tid & 3;    // A staging: row, k-quad
    int bk = tid >> 4, bq = tid & 15;   // B staging: k, col-quad
    int rg = tid >> 4, cg = tid & 15;   // compute: row group, col group

    float cre[4][4] = {{0}}, cim[4][4] = {{0}};
    for (int step = 0; step < 54; ++step) {
        int kb = k0 + step*16;
        float4 va_re = *(const float4*)(Are + (size_t)(r0+ap)*M_DIM + kb + aq*4);
        float4 va_im = *(const float4*)(Aim + (size_t)(r0+ap)*M_DIM + kb + aq*4);
        float4 vb_re = *(const float4*)(Bre + (size_t)(kb+bk)*NC + c0 + bq*4);
        float4 vb_im = *(const float4*)(Bim + (size_t)(kb+bk)*NC + c0 + bq*4);
        __syncthreads();
        sAre[(aq*4+0)*68 + ap] = va_re.x;
        sAre[(aq*4+1)*68 + ap] = va_re.y;
        sAre[(aq*4+2)*68 + ap] = va_re.z;
        sAre[(aq*4+3)*68 + ap] = va_re.w;
        sAim[(aq*4+0)*68 + ap] = va_im.x;
        sAim[(aq*4+1)*68 + ap] = va_im.y;
        sAim[(aq*4+2)*68 + ap] = va_im.z;
        sAim[(aq*4+3)*68 + ap] = va_im.w;
        *(float4*)(sBre + bk*68 + bq*4) = vb_re;
        *(float4*)(sBim + bk*68 + bq*4) = vb_im;
        __syncthreads();
        #pragma unroll 4
        for (int kk = 0; kk < 16; ++kk) {
            float4 ar4 = *(const float4*)(sAre + kk*68 + rg*4);
            float4 ai4 = *(const float4*)(sAim + kk*68 + rg*4);
            float4 br4 = *(const float4*)(sBre + kk*68 + cg*4);
            float4 bi4 = *(const float4*)(sBim + kk*68 + cg*4);
            float ar[4] = {ar4.x, ar4.y, ar4.z, ar4.w};
            float ai[4] = {ai4.x, ai4.y, ai4.z, ai4.w};
            float br[4] = {br4.x, br4.y, br4.z, br4.w};
            float bi[4] = {bi4.x, bi4.y, bi4.z, bi4.w};
            #pragma unroll
            for (int u = 0; u < 4; ++u)
                #pragma unroll
                for (int v = 0; v < 4; ++v) {
                    cre[u][v] += ar[u]*br[v] + ai[u]*bi[v];   // conj(A)
                    cim[u][v] += ar[u]*bi[v] - ai[u]*br[v];
                }
        }
    }
    #pragma unroll
    for (int u = 0; u < 4; ++u)
        #pragma unroll
        for (int v = 0; v < 4; ++v) {
            size_t o = (size_t)(r0 + rg*4 + u)*NC + c0 + cg*4 + v;
            atomicAdd(&Cre[o], cre[u][v]);
            atomicAdd(&Cim[o], cim[u][v]);
        }
}

// ---------------- mu from traces ----------------
__global__ void k_mu(const float* __restrict__ dPre, const float* __restrict__ dQre,
                     float* __restrict__ acc) {
    int t = threadIdx.x;  // 512 threads
    float v1 = (t < NP) ? dPre[t*(NP+1)] : 0.0f;
    float v2 = (t < NQ) ? dQre[t*(NQ+1)] : 0.0f;
    __shared__ float sm[8];
    float trP = blockSum(v1, sm);
    float trQ = blockSum(v2, sm);
    if (t == 0) {
        float N1 = acc[2];
        float n1 = W_FR * acc[0] / N1;
        float d1 = W_FR * acc[1] / N1;
        float n2 = W_FP * trP / (float)(NP*NP);
        float n3 = W_FQ * trQ / (float)(NQ*NQ);
        float d2 = W_FP / (float)NP;
        float d3 = W_FQ / (float)NQ;
        acc[3] = (n1 + n2 + n3) / (d1 + d2 + d3);
    }
}

// ---------------- loss_hr = sum |H_gt + mu*overlap - pred_H| ----------------
__global__ __launch_bounds__(256) void k_loss_hr(const float4* __restrict__ Hg,
                                                 const float4* __restrict__ Hp,
                                                 const float4* __restrict__ ov,
                                                 float* __restrict__ acc) {
    const int N4 = E_N*HRSZ/4;
    float mu = acc[3];
    int stride = gridDim.x * blockDim.x;
    float s = 0;
    for (int i = blockIdx.x*blockDim.x + threadIdx.x; i < N4; i += stride) {
        float4 hg = Hg[i], hp = Hp[i], o = ov[i];
        s += fabsf(hg.x + mu*o.x - hp.x) + fabsf(hg.y + mu*o.y - hp.y)
           + fabsf(hg.z + mu*o.z - hp.z) + fabsf(hg.w + mu*o.w - hp.w);
    }
    __shared__ float sm[8];
    float r = blockSum(s, sm);
    if (threadIdx.x == 0) atomicAdd(&acc[4], r);
}

// ---------------- L1 sums over dP, dQ, dPQ ----------------
__global__ __launch_bounds__(256) void k_loss_mats(
        const float* __restrict__ dPre, const float* __restrict__ dPim,
        const float* __restrict__ dQre, const float* __restrict__ dQim,
        const float* __restrict__ dPQre, const float* __restrict__ dPQim,
        float* __restrict__ acc) {
    const int NPP = NP*NP, NQQ = NQ*NQ, NPQ = NP*NQ;
    float mu = acc[3];
    float sP = 0, sQ = 0, sPQ = 0;
    int stride = gridDim.x * blockDim.x;
    for (int i = blockIdx.x*blockDim.x + threadIdx.x; i < NPP+NQQ+NPQ; i += stride) {
        if (i < NPP) {
            int r = i >> 8, c = i & 255;
            float d = (r == c) ? mu : 0.0f;
            sP += fabsf(d - dPre[i]) + fabsf(dPim[i]);
        } else if (i < NPP+NQQ) {
            int j = i - NPP;
            int r = j / NQ, c = j - r*NQ;
            float d = (r == c) ? mu : 0.0f;
            sQ += fabsf(d - dQre[j]) + fabsf(dQim[j]);
        } else {
            int j = i - (NPP+NQQ);
            sPQ += fabsf(dPQre[j]) + fabsf(dPQim[j]);
        }
    }
    __shared__ float sm[8];
    float a1 = blockSum(sP, sm);
    float a2 = blockSum(sQ, sm);
    float a3 = blockSum(sPQ, sm);
    if (threadIdx.x == 0) {
        atomicAdd(&acc[5], a1);
        atomicAdd(&acc[6], a2);
        atomicAdd(&acc[7], a3);
    }
}

// ---------------- final combine ----------------
__global__ void k_final(const float* __restrict__ acc, float* __restrict__ out) {
    if (threadIdx.x == 0 && blockIdx.x == 0) {
        float N1 = acc[2];
        out[0] = W_FR*acc[4]/N1
               + W_FP*acc[5]/(float)(NP*NP)
               + W_FQ*acc[6]/(float)(NQ*NQ)
               + W_FO*acc[7]/(float)(NP*NQ);
    }
}

extern "C" void kernel_launch(void* const* d_in, const int* in_sizes, int n_in,
                              void* d_out, int out_size, void* d_ws, size_t ws_size,
                              hipStream_t stream) {
    const float* edge_vec = (const float*)d_in[0];
    const float* lattice  = (const float*)d_in[1];
    const float* apos     = (const float*)d_in[2];
    const float* hr_gt    = (const float*)d_in[3];
    const float* hr_pred  = (const float*)d_in[4];
    const float* kpt      = (const float*)d_in[5];
    const float* P_re     = (const float*)d_in[6];
    const float* P_im     = (const float*)d_in[7];
    const float* Q_re     = (const float*)d_in[8];
    const float* Q_im     = (const float*)d_in[9];
    const float* H_gt     = (const float*)d_in[10];
    const float* pred_H   = (const float*)d_in[11];
    const float* overlap  = (const float*)d_in[12];
    const float* mask     = (const float*)d_in[13];
    const int*   esrc     = (const int*)d_in[14];
    const int*   edst     = (const int*)d_in[15];
    float* out = (float*)d_out;

    float* ws   = (float*)d_ws;
    float* acc  = ws;                       // 16 floats
    float* phre = ws + 16;                  // 1536
    float* phim = phre + E_N;               // 1536
    float* BPre = ws + 4096;                // M*NP
    float* BPim = BPre + (size_t)M_DIM*NP;
    float* BQre = BPim + (size_t)M_DIM*NP;  // M*NQ
    float* BQim = BQre + (size_t)M_DIM*NQ;
    float* dPre = BQim + (size_t)M_DIM*NQ;
    float* dPim = dPre + NP*NP;
    float* dQre = dPim + NP*NP;
    float* dQim = dQre + NQ*NQ;
    float* dPQre = dQim + NQ*NQ;
    float* dPQim = dPQre + NP*NQ;

    hipMemsetAsync(acc, 0, 16*sizeof(float), stream);
    hipMemsetAsync(dPre, 0, (size_t)(2*NP*NP + 2*NQ*NQ + 2*NP*NQ)*sizeof(float), stream);

    k_phase<<<E_N/256, 256, 0, stream>>>(edge_vec, lattice, apos, kpt, esrc, edst, phre, phim);
    k_red1<<<1024, 256, 0, stream>>>((const float4*)H_gt, (const float4*)pred_H,
                                     (const float4*)overlap, (const float4*)mask, acc);
    k_bp<<<NATOMS*10, 256, 0, stream>>>(hr_gt, hr_pred, P_re, P_im, Q_re, Q_im,
                                        esrc, edst, phre, phim, BPre, BPim, BQre, BQim);
    k_gemm<<<304, 256, 0, stream>>>(P_re, P_im, Q_re, Q_im, BPre, BPim, BQre, BQim,
                                    dPre, dPim, dQre, dQim, dPQre, dPQim);
    k_mu<<<1, 512, 0, stream>>>(dPre, dQre, acc);
    k_loss_hr<<<1024, 256, 0, stream>>>((const float4*)H_gt, (const float4*)pred_H,
                                        (const float4*)overlap, acc);
    k_loss_mats<<<256, 256, 0, stream>>>(dPre, dPim, dQre, dQim, dPQre, dPQim, acc);
    k_final<<<1, 1, 0, stream>>>(acc, out);
}

// Round 3
// 481.012 us; speedup vs baseline: 2.0193x; 2.0193x over previous
//
#include <hip/hip_runtime.h>
#include <math.h>

#define E_N    1536
#define ORBN   54
#define NATOMS 64
#define M_DIM  3456          // 54*64
#define NP     256
#define NQ     384
#define HRSZ   2916          // 54*54

#define W_FP 0.0002f
#define W_FQ 0.0001f
#define W_FO 0.00015f
#define W_FR (1.0f - W_FP - W_FQ - W_FO)

typedef __attribute__((ext_vector_type(8))) short short8;
typedef __attribute__((ext_vector_type(4))) float f32x4;

// pack 2 f32 -> 2 bf16 (RNE), low = a
__device__ __forceinline__ unsigned pk_bf16(float a, float b) {
    unsigned r;
    asm volatile("v_cvt_pk_bf16_f32 %0, %1, %2" : "=v"(r) : "v"(a), "v"(b));
    return r;
}
// scalar f32 -> bf16 RNE (safe, no asm)
__device__ __forceinline__ unsigned short f2bf(float x) {
    unsigned u = __builtin_bit_cast(unsigned, x);
    unsigned r = (u + 0x7fffu + ((u >> 16) & 1u)) >> 16;
    return (unsigned short)r;
}

// ---------------- block reduction helper ----------------
__device__ __forceinline__ float blockSum(float v, float* sm) {
    v += __shfl_down(v, 32); v += __shfl_down(v, 16); v += __shfl_down(v, 8);
    v += __shfl_down(v, 4);  v += __shfl_down(v, 2);  v += __shfl_down(v, 1);
    __syncthreads();
    if ((threadIdx.x & 63) == 0) sm[threadIdx.x >> 6] = v;
    __syncthreads();
    float r = 0.0f;
    if (threadIdx.x == 0) {
        int nw = blockDim.x >> 6;
        for (int i = 0; i < nw; ++i) r += sm[i];
    }
    return r;
}

// ---------------- phase factors per edge ----------------
__global__ void k_phase(const float* __restrict__ edge_vec,
                        const float* __restrict__ lat,
                        const float* __restrict__ apos,
                        const float* __restrict__ kpt,
                        const int* __restrict__ esrc,
                        const int* __restrict__ edst,
                        float* __restrict__ ph_re, float* __restrict__ ph_im) {
    int e = blockIdx.x * blockDim.x + threadIdx.x;
    if (e >= E_N) return;
    float a00 = lat[0], a01 = lat[3], a02 = lat[6];
    float a10 = lat[1], a11 = lat[4], a12 = lat[7];
    float a20 = lat[2], a21 = lat[5], a22 = lat[8];
    float c00 = a11*a22 - a12*a21;
    float c01 = a12*a20 - a10*a22;
    float c02 = a10*a21 - a11*a20;
    float det = a00*c00 + a01*c01 + a02*c02;
    float id  = 1.0f / det;
    float i00 = c00*id;
    float i01 = (a02*a21 - a01*a22)*id;
    float i02 = (a01*a12 - a02*a11)*id;
    float i10 = c01*id;
    float i11 = (a00*a22 - a02*a20)*id;
    float i12 = (a02*a10 - a00*a12)*id;
    float i20 = c02*id;
    float i21 = (a01*a20 - a00*a21)*id;
    float i22 = (a00*a11 - a01*a10)*id;
    int s = esrc[e], d = edst[e];
    float r0 = edge_vec[e*3+0] - (apos[d*3+0] - apos[s*3+0]);
    float r1 = edge_vec[e*3+1] - (apos[d*3+1] - apos[s*3+1]);
    float r2 = edge_vec[e*3+2] - (apos[d*3+2] - apos[s*3+2]);
    float t0 = roundf(i00*r0 + i01*r1 + i02*r2);
    float t1 = roundf(i10*r0 + i11*r1 + i12*r2);
    float t2 = roundf(i20*r0 + i21*r1 + i22*r2);
    float ph = t0*kpt[0] + t1*kpt[1] + t2*kpt[2];
    float ang = 6.28318530717958647692f * ph;
    ph_re[e] = cosf(ang);
    ph_im[e] = sinf(ang);
}

// ---------------- prep: convert P/Q to bf16 ----------------
__global__ __launch_bounds__(256) void k_prep(
        const float4* __restrict__ P_re, const float4* __restrict__ P_im,
        const float4* __restrict__ Q_re, const float4* __restrict__ Q_im,
        ushort4* __restrict__ Prebf, ushort4* __restrict__ Pimbf,
        ushort4* __restrict__ Qrebf, ushort4* __restrict__ Qimbf) {
    const int NP4 = NP*M_DIM/4;   // 221184
    const int NQ4 = NQ*M_DIM/4;   // 331776
    const int TOT = 2*NP4 + 2*NQ4;
    int stride = gridDim.x * blockDim.x;
    for (int i = blockIdx.x*blockDim.x + threadIdx.x; i < TOT; i += stride) {
        float4 v; ushort4* dst; int o;
        if (i < NP4)              { v = P_re[i];            dst = Prebf; o = i; }
        else if (i < 2*NP4)       { o = i - NP4;   v = P_im[o]; dst = Pimbf; }
        else if (i < 2*NP4+NQ4)   { o = i - 2*NP4; v = Q_re[o]; dst = Qrebf; }
        else                      { o = i - 2*NP4 - NQ4; v = Q_im[o]; dst = Qimbf; }
        ushort4 u;
        u.x = f2bf(v.x); u.y = f2bf(v.y); u.z = f2bf(v.z); u.w = f2bf(v.w);
        dst[o] = u;
    }
}

// ---------------- reduction: n1 numerator, overlap^2, mask sum ----------------
__global__ __launch_bounds__(256) void k_red1(const float4* __restrict__ Hg,
                                              const float4* __restrict__ Hp,
                                              const float4* __restrict__ ov,
                                              const float4* __restrict__ mk,
                                              float* __restrict__ acc) {
    const int N4 = E_N*HRSZ/4;
    int stride = gridDim.x * blockDim.x;
    float s0 = 0, s1 = 0, s2 = 0;
    for (int i = blockIdx.x*blockDim.x + threadIdx.x; i < N4; i += stride) {
        float4 hg = Hg[i], hp = Hp[i], o = ov[i], m = mk[i];
        s0 += (hp.x-hg.x)*o.x + (hp.y-hg.y)*o.y + (hp.z-hg.z)*o.z + (hp.w-hg.w)*o.w;
        s1 += o.x*o.x + o.y*o.y + o.z*o.z + o.w*o.w;
        s2 += m.x + m.y + m.z + m.w;
    }
    __shared__ float sm[8];
    float r0 = blockSum(s0, sm);
    float r1 = blockSum(s1, sm);
    float r2 = blockSum(s2, sm);
    if (threadIdx.x == 0) {
        atomicAdd(&acc[0], r0);
        atomicAdd(&acc[1], r1);
        atomicAdd(&acc[2], r2);
    }
}

// ---------------- k_bp: BP^T = (hk_d @ P^T)^T via per-edge MFMA, bf16 ----------------
// grid 64 atoms x 10 tiles. block 256 = 4 waves (2x2 of 32x32 outputs).
// A (complex, phase folded in): Are = ph_re*hrd, An = -ph_im*hrd; B = P/Q panel (complex bf16)
// Re = Are@Bre + An@Bim ; Im = Are@Bim - An@Bre
#define KPAD 72
__global__ __launch_bounds__(256) void k_bp(
        const float* __restrict__ hr_gt, const float* __restrict__ hr_pred,
        const ushort* __restrict__ Prebf, const ushort* __restrict__ Pimbf,
        const ushort* __restrict__ Qrebf, const ushort* __restrict__ Qimbf,
        const int* __restrict__ esrc, const int* __restrict__ edst,
        const float* __restrict__ phre, const float* __restrict__ phim,
        ushort* __restrict__ BPTPre, ushort* __restrict__ BPTPim,
        ushort* __restrict__ BPTQre, ushort* __restrict__ BPTQim) {
    __shared__ ushort Asr[64*KPAD], Asn[64*KPAD], Bsr[64*KPAD], Bsi[64*KPAD];
    __shared__ int elist[E_N];
    __shared__ int ecnt;

    int tid = threadIdx.x;
    int a   = blockIdx.x / 10;
    int t   = blockIdx.x - a*10;
    const ushort *Pr, *Pi; ushort *Or, *Oi; int col0;
    if (t < 4) { Pr = Prebf; Pi = Pimbf; Or = BPTPre; Oi = BPTPim; col0 = t*64; }
    else       { Pr = Qrebf; Pi = Qimbf; Or = BPTQre; Oi = BPTQim; col0 = (t-4)*64; }

    // zero LDS tiles (pad regions must stay zero)
    for (int i = tid; i < 64*KPAD/8; i += 256) {
        ((uint4*)Asr)[i] = uint4{0,0,0,0};
        ((uint4*)Asn)[i] = uint4{0,0,0,0};
        ((uint4*)Bsr)[i] = uint4{0,0,0,0};
        ((uint4*)Bsi)[i] = uint4{0,0,0,0};
    }
    if (tid == 0) ecnt = 0;
    __syncthreads();
    for (int k = tid; k < E_N; k += 256)
        if (esrc[k] == a) { int p = atomicAdd(&ecnt, 1); elist[p] = k; }
    __syncthreads();
    int ne = ecnt;

    int w  = tid >> 6, l = tid & 63;
    int wr0 = (w >> 1) * 32, wc0 = (w & 1) * 32;
    int lr  = l & 15, lk = (l >> 4) * 8, lk4 = (l >> 4) * 4;

    f32x4 accRe[2][2] = {}, accIA[2][2] = {}, accIB[2][2] = {};

    for (int n = 0; n < ne; ++n) {
        int e = elist[n];
        int dst = edst[e];
        float phr = phre[e], phi_ = phim[e];
        float nphi = -phi_;
        __syncthreads();   // previous MFMA frag reads done before restaging
        // A stage: 54 rows x 27 j-pairs = 1458
        {
            const float* hg = hr_gt  + (size_t)e*HRSZ;
            const float* hp = hr_pred + (size_t)e*HRSZ;
            for (int p = tid; p < 1458; p += 256) {
                int i = p / 27, jp = p - i*27;
                int o = i*54 + 2*jp;
                float2 g = *(const float2*)(hg + o);
                float2 q = *(const float2*)(hp + o);
                float d0 = q.x - g.x, d1 = q.y - g.y;
                int li = i*KPAD + 2*jp;
                *(unsigned*)(Asr + li) = pk_bf16(phr*d0, phr*d1);
                *(unsigned*)(Asn + li) = pk_bf16(nphi*d0, nphi*d1);
            }
        }
        // B stage: 64 cols x 27 j-pairs = 1728 (plain bf16 copy)
        {
            size_t rb = (size_t)dst*54;
            for (int p = tid; p < 1728; p += 256) {
                int c = p / 27, jp = p - c*27;
                size_t go = (size_t)(col0 + c)*M_DIM + rb + 2*jp;
                unsigned vr = *(const unsigned*)(Pr + go);
                unsigned vi = *(const unsigned*)(Pi + go);
                int li = c*KPAD + 2*jp;
                *(unsigned*)(Bsr + li) = vr;
                *(unsigned*)(Bsi + li) = vi;
            }
        }
        __syncthreads();

        #pragma unroll
        for (int kb = 0; kb < 2; ++kb) {
            int ko = kb*32 + lk;
            short8 ar[2], an[2], br[2], bi[2];
            #pragma unroll
            for (int mr = 0; mr < 2; ++mr) {
                int r = wr0 + mr*16 + lr;
                ar[mr] = *(const short8*)(Asr + r*KPAD + ko);
                an[mr] = *(const short8*)(Asn + r*KPAD + ko);
            }
            #pragma unroll
            for (int nc = 0; nc < 2; ++nc) {
                int c = wc0 + nc*16 + lr;
                br[nc] = *(const short8*)(Bsr + c*KPAD + ko);
                bi[nc] = *(const short8*)(Bsi + c*KPAD + ko);
            }
            #pragma unroll
            for (int mr = 0; mr < 2; ++mr)
                #pragma unroll
                for (int nc = 0; nc < 2; ++nc) {
                    accRe[mr][nc] = __builtin_amdgcn_mfma_f32_16x16x32_bf16(ar[mr], br[nc], accRe[mr][nc], 0, 0, 0);
                    accRe[mr][nc] = __builtin_amdgcn_mfma_f32_16x16x32_bf16(an[mr], bi[nc], accRe[mr][nc], 0, 0, 0);
                    accIA[mr][nc] = __builtin_amdgcn_mfma_f32_16x16x32_bf16(ar[mr], bi[nc], accIA[mr][nc], 0, 0, 0);
                    accIB[mr][nc] = __builtin_amdgcn_mfma_f32_16x16x32_bf16(an[mr], br[nc], accIB[mr][nc], 0, 0, 0);
                }
        }
    }

    // epilogue: write BPT bf16  [c_global][m]; C/D layout: col=l&15, row=(l>>4)*4+reg
    #pragma unroll
    for (int mr = 0; mr < 2; ++mr)
        #pragma unroll
        for (int nc = 0; nc < 2; ++nc) {
            int ib = wr0 + mr*16 + lk4;
            if (ib < 54) {
                int cg = col0 + wc0 + nc*16 + lr;
                size_t base = (size_t)cg*M_DIM + (size_t)a*54 + ib;
                float r0v = accRe[mr][nc][0], r1v = accRe[mr][nc][1];
                float r2v = accRe[mr][nc][2], r3v = accRe[mr][nc][3];
                float i0v = accIA[mr][nc][0] - accIB[mr][nc][0];
                float i1v = accIA[mr][nc][1] - accIB[mr][nc][1];
                float i2v = accIA[mr][nc][2] - accIB[mr][nc][2];
                float i3v = accIA[mr][nc][3] - accIB[mr][nc][3];
                *(unsigned*)(Or + base) = pk_bf16(r0v, r1v);
                *(unsigned*)(Oi + base) = pk_bf16(i0v, i1v);
                if (ib + 2 < 54) {
                    *(unsigned*)(Or + base + 2) = pk_bf16(r2v, r3v);
                    *(unsigned*)(Oi + base + 2) = pk_bf16(i2v, i3v);
                }
            }
        }
}

// ---------------- k_gemm: dP=conj(P)@BP etc. bf16 MFMA, 64x64 tile, K-split 6 ----------------
// conj: Re = Are@Bre + Aim@Bim (add-only); Im = Are@Bim - Aim@Bre (3-acc)
#define GPAD 40
__global__ __launch_bounds__(256) void k_gemm(
        const ushort* __restrict__ Prebf, const ushort* __restrict__ Pimbf,
        const ushort* __restrict__ Qrebf, const ushort* __restrict__ Qimbf,
        const ushort* __restrict__ BPTPre, const ushort* __restrict__ BPTPim,
        const ushort* __restrict__ BPTQre, const ushort* __restrict__ BPTQim,
        float* __restrict__ dPre, float* __restrict__ dPim,
        float* __restrict__ dQre, float* __restrict__ dQim,
        float* __restrict__ dPQre, float* __restrict__ dPQim) {
    __shared__ ushort Ar[64*GPAD], Ai[64*GPAD], Br[64*GPAD], Bi[64*GPAD];
    int tid = threadIdx.x;
    int bid = blockIdx.x;
    int t = bid / 6, ks = bid - t*6;
    const ushort *Ag, *Ai_g, *Bg, *Bi_g; float *Cre, *Cim; int NC, r0, c0;
    if (t < 16) {
        Ag = Prebf; Ai_g = Pimbf; Bg = BPTPre; Bi_g = BPTPim; Cre = dPre; Cim = dPim;
        NC = NP; r0 = (t & 3)*64; c0 = (t >> 2)*64;
    } else if (t < 52) {
        int u = t - 16;
        Ag = Qrebf; Ai_g = Qimbf; Bg = BPTQre; Bi_g = BPTQim; Cre = dQre; Cim = dQim;
        NC = NQ; r0 = (u % 6)*64; c0 = (u / 6)*64;
    } else {
        int u = t - 52;
        Ag = Prebf; Ai_g = Pimbf; Bg = BPTQre; Bi_g = BPTQim; Cre = dPQre; Cim = dPQim;
        NC = NQ; r0 = (u & 3)*64; c0 = (u >> 2)*64;
    }
    int k0 = ks * 576;
    int srow = tid >> 2, skq = (tid & 3) * 8;
    int w = tid >> 6, l = tid & 63;
    int wr0 = (w >> 1)*32, wc0 = (w & 1)*32;
    int lr = l & 15, lk = (l >> 4)*8, lk4 = (l >> 4)*4;

    f32x4 aRe[2][2] = {}, aIA[2][2] = {}, aIB[2][2] = {};
    for (int s = 0; s < 18; ++s) {
        int kb = k0 + s*32;
        __syncthreads();
        *(short8*)(Ar + srow*GPAD + skq) = *(const short8*)(Ag   + (size_t)(r0+srow)*M_DIM + kb + skq);
        *(short8*)(Ai + srow*GPAD + skq) = *(const short8*)(Ai_g + (size_t)(r0+srow)*M_DIM + kb + skq);
        *(short8*)(Br + srow*GPAD + skq) = *(const short8*)(Bg   + (size_t)(c0+srow)*M_DIM + kb + skq);
        *(short8*)(Bi + srow*GPAD + skq) = *(const short8*)(Bi_g + (size_t)(c0+srow)*M_DIM + kb + skq);
        __syncthreads();
        short8 fa[2], fn[2], fb[2], fi[2];
        #pragma unroll
        for (int mr = 0; mr < 2; ++mr) {
            int r = wr0 + mr*16 + lr;
            fa[mr] = *(const short8*)(Ar + r*GPAD + lk);
            fn[mr] = *(const short8*)(Ai + r*GPAD + lk);
        }
        #pragma unroll
        for (int nc = 0; nc < 2; ++nc) {
            int c = wc0 + nc*16 + lr;
            fb[nc] = *(const short8*)(Br + c*GPAD + lk);
            fi[nc] = *(const short8*)(Bi + c*GPAD + lk);
        }
        #pragma unroll
        for (int mr = 0; mr < 2; ++mr)
            #pragma unroll
            for (int nc = 0; nc < 2; ++nc) {
                aRe[mr][nc] = __builtin_amdgcn_mfma_f32_16x16x32_bf16(fa[mr], fb[nc], aRe[mr][nc], 0, 0, 0);
                aRe[mr][nc] = __builtin_amdgcn_mfma_f32_16x16x32_bf16(fn[mr], fi[nc], aRe[mr][nc], 0, 0, 0);
                aIA[mr][nc] = __builtin_amdgcn_mfma_f32_16x16x32_bf16(fa[mr], fi[nc], aIA[mr][nc], 0, 0, 0);
                aIB[mr][nc] = __builtin_amdgcn_mfma_f32_16x16x32_bf16(fn[mr], fb[nc], aIB[mr][nc], 0, 0, 0);
            }
    }
    #pragma unroll
    for (int mr = 0; mr < 2; ++mr)
        #pragma unroll
        for (int nc = 0; nc < 2; ++nc)
            #pragma unroll
            for (int rr = 0; rr < 4; ++rr) {
                int row = r0 + wr0 + mr*16 + lk4 + rr;
                int col = c0 + wc0 + nc*16 + lr;
                atomicAdd(&Cre[(size_t)row*NC + col], aRe[mr][nc][rr]);
                atomicAdd(&Cim[(size_t)row*NC + col], aIA[mr][nc][rr] - aIB[mr][nc][rr]);
            }
}

// ---------------- mu from traces ----------------
__global__ void k_mu(const float* __restrict__ dPre, const float* __restrict__ dQre,
                     float* __restrict__ acc) {
    int t = threadIdx.x;  // 512 threads
    float v1 = (t < NP) ? dPre[t*(NP+1)] : 0.0f;
    float v2 = (t < NQ) ? dQre[t*(NQ+1)] : 0.0f;
    __shared__ float sm[8];
    float trP = blockSum(v1, sm);
    float trQ = blockSum(v2, sm);
    if (t == 0) {
        float N1 = acc[2];
        float n1 = W_FR * acc[0] / N1;
        float d1 = W_FR * acc[1] / N1;
        float n2 = W_FP * trP / (float)(NP*NP);
        float n3 = W_FQ * trQ / (float)(NQ*NQ);
        float d2 = W_FP / (float)NP;
        float d3 = W_FQ / (float)NQ;
        acc[3] = (n1 + n2 + n3) / (d1 + d2 + d3);
    }
}

// ---------------- loss_hr = sum |H_gt + mu*overlap - pred_H| ----------------
__global__ __launch_bounds__(256) void k_loss_hr(const float4* __restrict__ Hg,
                                                 const float4* __restrict__ Hp,
                                                 const float4* __restrict__ ov,
                                                 float* __restrict__ acc) {
    const int N4 = E_N*HRSZ/4;
    float mu = acc[3];
    int stride = gridDim.x * blockDim.x;
    float s = 0;
    for (int i = blockIdx.x*blockDim.x + threadIdx.x; i < N4; i += stride) {
        float4 hg = Hg[i], hp = Hp[i], o = ov[i];
        s += fabsf(hg.x + mu*o.x - hp.x) + fabsf(hg.y + mu*o.y - hp.y)
           + fabsf(hg.z + mu*o.z - hp.z) + fabsf(hg.w + mu*o.w - hp.w);
    }
    __shared__ float sm[8];
    float r = blockSum(s, sm);
    if (threadIdx.x == 0) atomicAdd(&acc[4], r);
}

// ---------------- L1 sums over dP, dQ, dPQ ----------------
__global__ __launch_bounds__(256) void k_loss_mats(
        const float* __restrict__ dPre, const float* __restrict__ dPim,
        const float* __restrict__ dQre, const float* __restrict__ dQim,
        const float* __restrict__ dPQre, const float* __restrict__ dPQim,
        float* __restrict__ acc) {
    const int NPP = NP*NP, NQQ = NQ*NQ, NPQ = NP*NQ;
    float mu = acc[3];
    float sP = 0, sQ = 0, sPQ = 0;
    int stride = gridDim.x * blockDim.x;
    for (int i = blockIdx.x*blockDim.x + threadIdx.x; i < NPP+NQQ+NPQ; i += stride) {
        if (i < NPP) {
            int r = i >> 8, c = i & 255;
            float d = (r == c) ? mu : 0.0f;
            sP += fabsf(d - dPre[i]) + fabsf(dPim[i]);
        } else if (i < NPP+NQQ) {
            int j = i - NPP;
            int r = j / NQ, c = j - r*NQ;
            float d = (r == c) ? mu : 0.0f;
            sQ += fabsf(d - dQre[j]) + fabsf(dQim[j]);
        } else {
            int j = i - (NPP+NQQ);
            sPQ += fabsf(dPQre[j]) + fabsf(dPQim[j]);
        }
    }
    __shared__ float sm[8];
    float a1 = blockSum(sP, sm);
    float a2 = blockSum(sQ, sm);
    float a3 = blockSum(sPQ, sm);
    if (threadIdx.x == 0) {
        atomicAdd(&acc[5], a1);
        atomicAdd(&acc[6], a2);
        atomicAdd(&acc[7], a3);
    }
}

// ---------------- final combine ----------------
__global__ void k_final(const float* __restrict__ acc, float* __restrict__ out) {
    if (threadIdx.x == 0 && blockIdx.x == 0) {
        float N1 = acc[2];
        out[0] = W_FR*acc[4]/N1
               + W_FP*acc[5]/(float)(NP*NP)
               + W_FQ*acc[6]/(float)(NQ*NQ)
               + W_FO*acc[7]/(float)(NP*NQ);
    }
}

extern "C" void kernel_launch(void* const* d_in, const int* in_sizes, int n_in,
                              void* d_out, int out_size, void* d_ws, size_t ws_size,
                              hipStream_t stream) {
    const float* edge_vec = (const float*)d_in[0];
    const float* lattice  = (const float*)d_in[1];
    const float* apos     = (const float*)d_in[2];
    const float* hr_gt    = (const float*)d_in[3];
    const float* hr_pred  = (const float*)d_in[4];
    const float* kpt      = (const float*)d_in[5];
    const float* P_re     = (const float*)d_in[6];
    const float* P_im     = (const float*)d_in[7];
    const float* Q_re     = (const float*)d_in[8];
    const float* Q_im     = (const float*)d_in[9];
    const float* H_gt     = (const float*)d_in[10];
    const float* pred_H   = (const float*)d_in[11];
    const float* overlap  = (const float*)d_in[12];
    const float* mask     = (const float*)d_in[13];
    const int*   esrc     = (const int*)d_in[14];
    const int*   edst     = (const int*)d_in[15];
    float* out = (float*)d_out;

    float* ws   = (float*)d_ws;
    float* acc  = ws;                       // 16 floats
    float* phre = ws + 16;                  // 1536
    float* phim = phre + E_N;               // 1536
    float* dPre  = ws + 4096;               // 65536
    float* dPim  = dPre + NP*NP;
    float* dQre  = dPim + NP*NP;            // 147456
    float* dQim  = dQre + NQ*NQ;
    float* dPQre = dQim + NQ*NQ;            // 98304
    float* dPQim = dPQre + NP*NQ;
    ushort* us = (ushort*)(dPQim + NP*NQ);  // byte off 2506752
    ushort* Prebf  = us;                            // 884736
    ushort* Pimbf  = Prebf  + (size_t)NP*M_DIM;
    ushort* Qrebf  = Pimbf  + (size_t)NP*M_DIM;     // 1327104
    ushort* Qimbf  = Qrebf  + (size_t)NQ*M_DIM;
    ushort* BPTPre = Qimbf  + (size_t)NQ*M_DIM;
    ushort* BPTPim = BPTPre + (size_t)NP*M_DIM;
    ushort* BPTQre = BPTPim + (size_t)NP*M_DIM;
    ushort* BPTQim = BPTQre + (size_t)NQ*M_DIM;

    hipMemsetAsync(acc, 0, 16*sizeof(float), stream);
    hipMemsetAsync(dPre, 0, (size_t)(2*NP*NP + 2*NQ*NQ + 2*NP*NQ)*sizeof(float), stream);

    k_phase<<<E_N/256, 256, 0, stream>>>(edge_vec, lattice, apos, kpt, esrc, edst, phre, phim);
    k_prep<<<1024, 256, 0, stream>>>((const float4*)P_re, (const float4*)P_im,
                                     (const float4*)Q_re, (const float4*)Q_im,
                                     (ushort4*)Prebf, (ushort4*)Pimbf,
                                     (ushort4*)Qrebf, (ushort4*)Qimbf);
    k_red1<<<1024, 256, 0, stream>>>((const float4*)H_gt, (const float4*)pred_H,
                                     (const float4*)overlap, (const float4*)mask, acc);
    k_bp<<<NATOMS*10, 256, 0, stream>>>(hr_gt, hr_pred, Prebf, Pimbf, Qrebf, Qimbf,
                                        esrc, edst, phre, phim,
                                        BPTPre, BPTPim, BPTQre, BPTQim);
    k_gemm<<<456, 256, 0, stream>>>(Prebf, Pimbf, Qrebf, Qimbf,
                                    BPTPre, BPTPim, BPTQre, BPTQim,
                                    dPre, dPim, dQre, dQim, dPQre, dPQim);
    k_mu<<<1, 512, 0, stream>>>(dPre, dQre, acc);
    k_loss_hr<<<1024, 256, 0, stream>>>((const float4*)H_gt, (const float4*)pred_H,
                                        (const float4*)overlap, acc);
    k_loss_mats<<<256, 256, 0, stream>>>(dPre, dPim, dQre, dQim, dPQre, dPQim, acc);
    k_final<<<1, 1, 0, stream>>>(acc, out);
}

// Round 4
// 338.272 us; speedup vs baseline: 2.8714x; 1.4220x over previous
//
#include <hip/hip_runtime.h>
#include <math.h>

#define E_N    1536
#define NATOMS 64
#define M_DIM  3456          // 54*64
#define NP     256
#define NQ     384
#define HRSZ   2916          // 54*54

#define W_FP 0.0002f
#define W_FQ 0.0001f
#define W_FO 0.00015f
#define W_FR (1.0f - W_FP - W_FQ - W_FO)

typedef __attribute__((ext_vector_type(8))) short short8;
typedef __attribute__((ext_vector_type(4))) float f32x4;

// pack 2 f32 -> 2 bf16 (RNE), low = a
__device__ __forceinline__ unsigned pk_bf16(float a, float b) {
    unsigned r;
    asm volatile("v_cvt_pk_bf16_f32 %0, %1, %2" : "=v"(r) : "v"(a), "v"(b));
    return r;
}
__device__ __forceinline__ unsigned short f2bf(float x) {
    unsigned u = __builtin_bit_cast(unsigned, x);
    unsigned r = (u + 0x7fffu + ((u >> 16) & 1u)) >> 16;
    return (unsigned short)r;
}

// async global->LDS, 16B per lane; LDS dest is wave-uniform base + lane*16
__device__ __forceinline__ void gload_lds16(const void* g, void* l) {
    __builtin_amdgcn_global_load_lds(
        (const __attribute__((address_space(1))) unsigned int*)g,
        (__attribute__((address_space(3))) unsigned int*)l, 16, 0, 0);
}

// ---------------- block reduction helper ----------------
__device__ __forceinline__ float blockSum(float v, float* sm) {
    v += __shfl_down(v, 32); v += __shfl_down(v, 16); v += __shfl_down(v, 8);
    v += __shfl_down(v, 4);  v += __shfl_down(v, 2);  v += __shfl_down(v, 1);
    __syncthreads();
    if ((threadIdx.x & 63) == 0) sm[threadIdx.x >> 6] = v;
    __syncthreads();
    float r = 0.0f;
    if (threadIdx.x == 0) {
        int nw = blockDim.x >> 6;
        for (int i = 0; i < nw; ++i) r += sm[i];
    }
    return r;
}

// ---------------- phase factors + edge buckets ----------------
__global__ void k_phase(const float* __restrict__ edge_vec,
                        const float* __restrict__ lat,
                        const float* __restrict__ apos,
                        const float* __restrict__ kpt,
                        const int* __restrict__ esrc,
                        const int* __restrict__ edst,
                        float* __restrict__ ph_re, float* __restrict__ ph_im,
                        int* __restrict__ bcnt, int* __restrict__ blist) {
    int e = blockIdx.x * blockDim.x + threadIdx.x;
    if (e >= E_N) return;
    float a00 = lat[0], a01 = lat[3], a02 = lat[6];
    float a10 = lat[1], a11 = lat[4], a12 = lat[7];
    float a20 = lat[2], a21 = lat[5], a22 = lat[8];
    float c00 = a11*a22 - a12*a21;
    float c01 = a12*a20 - a10*a22;
    float c02 = a10*a21 - a11*a20;
    float det = a00*c00 + a01*c01 + a02*c02;
    float id  = 1.0f / det;
    float i00 = c00*id;
    float i01 = (a02*a21 - a01*a22)*id;
    float i02 = (a01*a12 - a02*a11)*id;
    float i10 = c01*id;
    float i11 = (a00*a22 - a02*a20)*id;
    float i12 = (a02*a10 - a00*a12)*id;
    float i20 = c02*id;
    float i21 = (a01*a20 - a00*a21)*id;
    float i22 = (a00*a11 - a01*a10)*id;
    int s = esrc[e], d = edst[e];
    float r0 = edge_vec[e*3+0] - (apos[d*3+0] - apos[s*3+0]);
    float r1 = edge_vec[e*3+1] - (apos[d*3+1] - apos[s*3+1]);
    float r2 = edge_vec[e*3+2] - (apos[d*3+2] - apos[s*3+2]);
    float t0 = roundf(i00*r0 + i01*r1 + i02*r2);
    float t1 = roundf(i10*r0 + i11*r1 + i12*r2);
    float t2 = roundf(i20*r0 + i21*r1 + i22*r2);
    float ph = t0*kpt[0] + t1*kpt[1] + t2*kpt[2];
    float ang = 6.28318530717958647692f * ph;
    ph_re[e] = cosf(ang);
    ph_im[e] = sinf(ang);
    int p = atomicAdd(&bcnt[s], 1);
    if (p < 128) blist[s*128 + p] = (e << 6) | d;
}

// ---------------- prep: convert P/Q to flat bf16 ----------------
__global__ __launch_bounds__(256) void k_prep(
        const float4* __restrict__ P_re, const float4* __restrict__ P_im,
        const float4* __restrict__ Q_re, const float4* __restrict__ Q_im,
        ushort4* __restrict__ Prebf, ushort4* __restrict__ Pimbf,
        ushort4* __restrict__ Qrebf, ushort4* __restrict__ Qimbf) {
    const int NP4 = NP*M_DIM/4;
    const int NQ4 = NQ*M_DIM/4;
    const int TOT = 2*NP4 + 2*NQ4;
    int stride = gridDim.x * blockDim.x;
    for (int i = blockIdx.x*blockDim.x + threadIdx.x; i < TOT; i += stride) {
        float4 v; ushort4* dst; int o;
        if (i < NP4)              { v = P_re[i];            dst = Prebf; o = i; }
        else if (i < 2*NP4)       { o = i - NP4;   v = P_im[o]; dst = Pimbf; }
        else if (i < 2*NP4+NQ4)   { o = i - 2*NP4; v = Q_re[o]; dst = Qrebf; }
        else                      { o = i - 2*NP4 - NQ4; v = Q_im[o]; dst = Qimbf; }
        ushort4 u;
        u.x = f2bf(v.x); u.y = f2bf(v.y); u.z = f2bf(v.z); u.w = f2bf(v.w);
        dst[o] = u;
    }
}

// ---------------- hrd = bf16(hr_pred - hr_gt), padded 64x64, chunk-XOR-swizzled ----------------
// per edge: 8192 B = 64 rows x 64 ush; row i, uint j2 (k=2j2,2j2+1) stored at
// uint idx = i*32 + ((j2>>2)^(i&7))*4 + (j2&3)
__global__ __launch_bounds__(256) void k_hrd(
        const float* __restrict__ hr_gt, const float* __restrict__ hr_pred,
        unsigned* __restrict__ hrdG) {
    int idx = blockIdx.x*blockDim.x + threadIdx.x;   // 1536*2048
    int e = idx >> 11;
    int p = idx & 2047;
    int i = p >> 5, j2 = p & 31;
    float d0 = 0.0f, d1 = 0.0f;
    if (i < 54 && j2 < 27) {
        int o = e*HRSZ + i*54 + 2*j2;
        float2 g = *(const float2*)(hr_gt + o);
        float2 q = *(const float2*)(hr_pred + o);
        d0 = q.x - g.x; d1 = q.y - g.y;
    }
    hrdG[e*2048 + i*32 + (((j2>>2) ^ (i & 7))<<2) + (j2 & 3)] = pk_bf16(d0, d1);
}

// ---------------- P/Q panels padded [dst][640 cols][64 ush], swizzled by col ----------------
__global__ __launch_bounds__(256) void k_pqpad(
        const ushort* __restrict__ Prebf, const ushort* __restrict__ Pimbf,
        const ushort* __restrict__ Qrebf, const ushort* __restrict__ Qimbf,
        unsigned* __restrict__ PpadR, unsigned* __restrict__ PpadI) {
    int idx = blockIdx.x*blockDim.x + threadIdx.x;   // 64*640*32
    int j2 = idx & 31;
    int r  = idx >> 5;
    int c  = r % 640;
    int dst = r / 640;
    unsigned vr = 0, vi = 0;
    if (j2 < 27) {
        const ushort* sre = (c < NP) ? (Prebf + (size_t)c*M_DIM) : (Qrebf + (size_t)(c-NP)*M_DIM);
        const ushort* sim = (c < NP) ? (Pimbf + (size_t)c*M_DIM) : (Qimbf + (size_t)(c-NP)*M_DIM);
        int o = dst*54 + 2*j2;
        vr = *(const unsigned*)(sre + o);
        vi = *(const unsigned*)(sim + o);
    }
    int loc = (dst*640 + c)*32 + (((j2>>2) ^ (c & 7))<<2) + (j2 & 3);
    PpadR[loc] = vr;
    PpadI[loc] = vi;
}

// ---------------- reduction: n1 numerator, overlap^2, mask sum ----------------
__global__ __launch_bounds__(256) void k_red1(const float4* __restrict__ Hg,
                                              const float4* __restrict__ Hp,
                                              const float4* __restrict__ ov,
                                              const float4* __restrict__ mk,
                                              float* __restrict__ acc) {
    const int N4 = E_N*HRSZ/4;
    int stride = gridDim.x * blockDim.x;
    float s0 = 0, s1 = 0, s2 = 0;
    for (int i = blockIdx.x*blockDim.x + threadIdx.x; i < N4; i += stride) {
        float4 hg = Hg[i], hp = Hp[i], o = ov[i], m = mk[i];
        s0 += (hp.x-hg.x)*o.x + (hp.y-hg.y)*o.y + (hp.z-hg.z)*o.z + (hp.w-hg.w)*o.w;
        s1 += o.x*o.x + o.y*o.y + o.z*o.z + o.w*o.w;
        s2 += m.x + m.y + m.z + m.w;
    }
    __shared__ float sm[8];
    float r0 = blockSum(s0, sm);
    float r1 = blockSum(s1, sm);
    float r2 = blockSum(s2, sm);
    if (threadIdx.x == 0) {
        atomicAdd(&acc[0], r0);
        atomicAdd(&acc[1], r1);
        atomicAdd(&acc[2], r2);
    }
}

// ---------------- k_bp: BP^T via per-edge MFMA (hrd real => 2 matmuls + VALU phase combine) ----------------
// grid 640 = 64 atoms x 10 col-tiles; 256 thr = 4 waves (2x2 of 32x32 output)
__global__ __launch_bounds__(256) void k_bp(
        const unsigned* __restrict__ hrdG,
        const unsigned* __restrict__ PpadR, const unsigned* __restrict__ PpadI,
        const float* __restrict__ phre, const float* __restrict__ phim,
        const int* __restrict__ bcnt, const int* __restrict__ blist,
        ushort* __restrict__ BPTPre, ushort* __restrict__ BPTPim,
        ushort* __restrict__ BPTQre, ushort* __restrict__ BPTQim) {
    __shared__ ushort lds[3*4096];   // [0]=hrd, [1]=PpadR, [2]=PpadI tiles (24 KB)

    int tid = threadIdx.x;
    int a   = blockIdx.x / 10;
    int t   = blockIdx.x - a*10;
    ushort *Or, *Oi; int col0;
    if (t < 4) { Or = BPTPre; Oi = BPTPim; col0 = t*64; }
    else       { Or = BPTQre; Oi = BPTQim; col0 = (t-4)*64; }
    int gp0 = (/*dst*/0)*0 + t*64;   // Ppad col base (t*64), dst added per edge

    int ne = bcnt[a]; if (ne > 128) ne = 128;
    const int* lst = blist + a*128;

    int w = tid >> 6, l = tid & 63;
    int wr0 = (w >> 1) * 32, wc0 = (w & 1) * 32;
    int lr = l & 15, kq = l >> 4, lk4 = (l >> 4) * 4;

    f32x4 accRe[2][2] = {}, accIm[2][2] = {};

    for (int n = 0; n < ne; ++n) {
        int v = lst[n];
        int ee = v >> 6, dst = v & 63;
        float phr = phre[ee], phi_ = phim[ee];
        const ushort* g0 = (const ushort*)(hrdG + (size_t)ee*2048);
        const ushort* g1 = (const ushort*)(PpadR + ((size_t)dst*640 + gp0)*32);
        const ushort* g2 = (const ushort*)(PpadI + ((size_t)dst*640 + gp0)*32);

        __syncthreads();   // previous edge's frag reads done before overwrite
        #pragma unroll
        for (int j = 0; j < 6; ++j) {
            int jj = w + j*4;            // 0..23
            int arr = jj >> 3, ch = jj & 7;
            const ushort* gb = (arr == 0) ? g0 : (arr == 1) ? g1 : g2;
            gload_lds16(gb + ch*512 + l*8, (void*)(lds + arr*4096 + ch*512));
        }
        asm volatile("s_waitcnt vmcnt(0)" ::: "memory");
        __syncthreads();

        // fragments + MFMA (2 real matmuls T1 = hrd@Bre, T2 = hrd@Bim)
        const ushort* A = lds;
        const ushort* BR = lds + 4096;
        const ushort* BI = lds + 8192;
        short8 a0[2], a1[2], br0[2], br1[2], bi0[2], bi1[2];
        #pragma unroll
        for (int mr = 0; mr < 2; ++mr) {
            int r = wr0 + mr*16 + lr;
            a0[mr] = *(const short8*)(A + r*64 + ((kq     ^ (r & 7))<<3));
            a1[mr] = *(const short8*)(A + r*64 + (((4+kq) ^ (r & 7))<<3));
        }
        #pragma unroll
        for (int nc = 0; nc < 2; ++nc) {
            int c = wc0 + nc*16 + lr;
            br0[nc] = *(const short8*)(BR + c*64 + ((kq     ^ (c & 7))<<3));
            br1[nc] = *(const short8*)(BR + c*64 + (((4+kq) ^ (c & 7))<<3));
            bi0[nc] = *(const short8*)(BI + c*64 + ((kq     ^ (c & 7))<<3));
            bi1[nc] = *(const short8*)(BI + c*64 + (((4+kq) ^ (c & 7))<<3));
        }
        f32x4 z = {0.0f, 0.0f, 0.0f, 0.0f};
        f32x4 t1[2][2], t2[2][2];
        #pragma unroll
        for (int mr = 0; mr < 2; ++mr)
            #pragma unroll
            for (int nc = 0; nc < 2; ++nc) {
                t1[mr][nc] = __builtin_amdgcn_mfma_f32_16x16x32_bf16(a0[mr], br0[nc], z, 0, 0, 0);
                t1[mr][nc] = __builtin_amdgcn_mfma_f32_16x16x32_bf16(a1[mr], br1[nc], t1[mr][nc], 0, 0, 0);
                t2[mr][nc] = __builtin_amdgcn_mfma_f32_16x16x32_bf16(a0[mr], bi0[nc], z, 0, 0, 0);
                t2[mr][nc] = __builtin_amdgcn_mfma_f32_16x16x32_bf16(a1[mr], bi1[nc], t2[mr][nc], 0, 0, 0);
            }
        #pragma unroll
        for (int mr = 0; mr < 2; ++mr)
            #pragma unroll
            for (int nc = 0; nc < 2; ++nc)
                #pragma unroll
                for (int q = 0; q < 4; ++q) {
                    accRe[mr][nc][q] += phr*t1[mr][nc][q] - phi_*t2[mr][nc][q];
                    accIm[mr][nc][q] += phr*t2[mr][nc][q] + phi_*t1[mr][nc][q];
                }
    }

    // epilogue: BPT bf16 [c][M]; C/D layout col=l&15, row=(l>>4)*4+reg
    #pragma unroll
    for (int mr = 0; mr < 2; ++mr)
        #pragma unroll
        for (int nc = 0; nc < 2; ++nc) {
            int ib = wr0 + mr*16 + lk4;
            if (ib < 54) {
                int cg = col0 + wc0 + nc*16 + lr;
                size_t base = (size_t)cg*M_DIM + (size_t)a*54 + ib;
                *(unsigned*)(Or + base) = pk_bf16(accRe[mr][nc][0], accRe[mr][nc][1]);
                *(unsigned*)(Oi + base) = pk_bf16(accIm[mr][nc][0], accIm[mr][nc][1]);
                if (ib + 2 < 54) {
                    *(unsigned*)(Or + base + 2) = pk_bf16(accRe[mr][nc][2], accRe[mr][nc][3]);
                    *(unsigned*)(Oi + base + 2) = pk_bf16(accIm[mr][nc][2], accIm[mr][nc][3]);
                }
            }
        }
}

// ---------------- k_gemm: bf16 MFMA, 64x64 tile, K-split 6, partial slices (no atomics) ----------------
#define GPAD 40
__global__ __launch_bounds__(256) void k_gemm(
        const ushort* __restrict__ Prebf, const ushort* __restrict__ Pimbf,
        const ushort* __restrict__ Qrebf, const ushort* __restrict__ Qimbf,
        const ushort* __restrict__ BPTPre, const ushort* __restrict__ BPTPim,
        const ushort* __restrict__ BPTQre, const ushort* __restrict__ BPTQim,
        float* __restrict__ part) {
    __shared__ ushort Ar[64*GPAD], Ai[64*GPAD], Br_[64*GPAD], Bi_[64*GPAD];
    int tid = threadIdx.x;
    int bid = blockIdx.x;
    int t = bid / 6, ks = bid - t*6;
    const ushort *Ag, *Aig, *Bg, *Big; float *Cre, *Cim; int NC, r0, c0;
    if (t < 16) {
        Ag = Prebf; Aig = Pimbf; Bg = BPTPre; Big = BPTPim;
        NC = NP; r0 = (t & 3)*64; c0 = (t >> 2)*64;
        Cre = part + (size_t)ks*2*65536; Cim = Cre + 65536;
    } else if (t < 52) {
        int u = t - 16;
        Ag = Qrebf; Aig = Qimbf; Bg = BPTQre; Big = BPTQim;
        NC = NQ; r0 = (u % 6)*64; c0 = (u / 6)*64;
        Cre = part + 786432 + (size_t)ks*2*147456; Cim = Cre + 147456;
    } else {
        int u = t - 52;
        Ag = Prebf; Aig = Pimbf; Bg = BPTQre; Big = BPTQim;
        NC = NQ; r0 = (u & 3)*64; c0 = (u >> 2)*64;
        Cre = part + 786432 + 1769472 + (size_t)ks*2*98304; Cim = Cre + 98304;
    }
    int k0 = ks * 576;
    int srow = tid >> 2, skq = (tid & 3) * 8;
    int w = tid >> 6, l = tid & 63;
    int wr0 = (w >> 1)*32, wc0 = (w & 1)*32;
    int lr = l & 15, lk = (l >> 4)*8, lk4 = (l >> 4)*4;

    const ushort* pa  = Ag  + (size_t)(r0+srow)*M_DIM + k0 + skq;
    const ushort* pai = Aig + (size_t)(r0+srow)*M_DIM + k0 + skq;
    const ushort* pb  = Bg  + (size_t)(c0+srow)*M_DIM + k0 + skq;
    const ushort* pbi = Big + (size_t)(c0+srow)*M_DIM + k0 + skq;

    short8 ra = *(const short8*)pa, rai = *(const short8*)pai;
    short8 rb = *(const short8*)pb, rbi = *(const short8*)pbi;

    f32x4 aRe[2][2] = {}, aIA[2][2] = {}, aIB[2][2] = {};
    for (int s = 0; s < 18; ++s) {
        __syncthreads();
        *(short8*)(Ar  + srow*GPAD + skq) = ra;
        *(short8*)(Ai  + srow*GPAD + skq) = rai;
        *(short8*)(Br_ + srow*GPAD + skq) = rb;
        *(short8*)(Bi_ + srow*GPAD + skq) = rbi;
        __syncthreads();
        if (s < 17) {
            int o = (s+1)*32;
            ra  = *(const short8*)(pa  + o);
            rai = *(const short8*)(pai + o);
            rb  = *(const short8*)(pb  + o);
            rbi = *(const short8*)(pbi + o);
        }
        short8 fa[2], fn[2], fb[2], fi[2];
        #pragma unroll
        for (int mr = 0; mr < 2; ++mr) {
            int r = wr0 + mr*16 + lr;
            fa[mr] = *(const short8*)(Ar + r*GPAD + lk);
            fn[mr] = *(const short8*)(Ai + r*GPAD + lk);
        }
        #pragma unroll
        for (int nc = 0; nc < 2; ++nc) {
            int c = wc0 + nc*16 + lr;
            fb[nc] = *(const short8*)(Br_ + c*GPAD + lk);
            fi[nc] = *(const short8*)(Bi_ + c*GPAD + lk);
        }
        #pragma unroll
        for (int mr = 0; mr < 2; ++mr)
            #pragma unroll
            for (int nc = 0; nc < 2; ++nc) {
                aRe[mr][nc] = __builtin_amdgcn_mfma_f32_16x16x32_bf16(fa[mr], fb[nc], aRe[mr][nc], 0, 0, 0);
                aRe[mr][nc] = __builtin_amdgcn_mfma_f32_16x16x32_bf16(fn[mr], fi[nc], aRe[mr][nc], 0, 0, 0);
                aIA[mr][nc] = __builtin_amdgcn_mfma_f32_16x16x32_bf16(fa[mr], fi[nc], aIA[mr][nc], 0, 0, 0);
                aIB[mr][nc] = __builtin_amdgcn_mfma_f32_16x16x32_bf16(fn[mr], fb[nc], aIB[mr][nc], 0, 0, 0);
            }
    }
    #pragma unroll
    for (int mr = 0; mr < 2; ++mr)
        #pragma unroll
        for (int nc = 0; nc < 2; ++nc)
            #pragma unroll
            for (int rr = 0; rr < 4; ++rr) {
                int row = r0 + wr0 + mr*16 + lk4 + rr;
                int col = c0 + wc0 + nc*16 + lr;
                Cre[(size_t)row*NC + col] = aRe[mr][nc][rr];
                Cim[(size_t)row*NC + col] = aIA[mr][nc][rr] - aIB[mr][nc][rr];
            }
}

// ---------------- mu from traces (sum 6 K-partials) ----------------
__global__ void k_mu(const float* __restrict__ part, float* __restrict__ acc) {
    int t = threadIdx.x;  // 512 threads
    float v1 = 0.0f, v2 = 0.0f;
    if (t < NP) {
        #pragma unroll
        for (int ks = 0; ks < 6; ++ks) v1 += part[ks*131072 + t*(NP+1)];
    }
    if (t < NQ) {
        const float* q = part + 786432;
        #pragma unroll
        for (int ks = 0; ks < 6; ++ks) v2 += q[ks*294912 + t*(NQ+1)];
    }
    __shared__ float sm[8];
    float trP = blockSum(v1, sm);
    float trQ = blockSum(v2, sm);
    if (t == 0) {
        float N1 = acc[2];
        float n1 = W_FR * acc[0] / N1;
        float d1 = W_FR * acc[1] / N1;
        float n2 = W_FP * trP / (float)(NP*NP);
        float n3 = W_FQ * trQ / (float)(NQ*NQ);
        float d2 = W_FP / (float)NP;
        float d3 = W_FQ / (float)NQ;
        acc[3] = (n1 + n2 + n3) / (d1 + d2 + d3);
    }
}

// ---------------- loss_hr = sum |H_gt + mu*overlap - pred_H| ----------------
__global__ __launch_bounds__(256) void k_loss_hr(const float4* __restrict__ Hg,
                                                 const float4* __restrict__ Hp,
                                                 const float4* __restrict__ ov,
                                                 float* __restrict__ acc) {
    const int N4 = E_N*HRSZ/4;
    float mu = acc[3];
    int stride = gridDim.x * blockDim.x;
    float s = 0;
    for (int i = blockIdx.x*blockDim.x + threadIdx.x; i < N4; i += stride) {
        float4 hg = Hg[i], hp = Hp[i], o = ov[i];
        s += fabsf(hg.x + mu*o.x - hp.x) + fabsf(hg.y + mu*o.y - hp.y)
           + fabsf(hg.z + mu*o.z - hp.z) + fabsf(hg.w + mu*o.w - hp.w);
    }
    __shared__ float sm[8];
    float r = blockSum(s, sm);
    if (threadIdx.x == 0) atomicAdd(&acc[4], r);
}

// ---------------- L1 sums over dP, dQ, dPQ (sum 6 K-partials per element) ----------------
__global__ __launch_bounds__(256) void k_loss_mats(
        const float* __restrict__ part, float* __restrict__ acc) {
    const int NPP = NP*NP, NQQ = NQ*NQ, NPQ = NP*NQ;
    float mu = acc[3];
    float sP = 0, sQ = 0, sPQ = 0;
    int stride = gridDim.x * blockDim.x;
    for (int i = blockIdx.x*blockDim.x + threadIdx.x; i < NPP+NQQ+NPQ; i += stride) {
        if (i < NPP) {
            float sre = 0, sim = 0;
            #pragma unroll
            for (int ks = 0; ks < 6; ++ks) {
                sre += part[ks*131072 + i];
                sim += part[ks*131072 + 65536 + i];
            }
            int r = i >> 8, c = i & 255;
            float d = (r == c) ? mu : 0.0f;
            sP += fabsf(d - sre) + fabsf(sim);
        } else if (i < NPP+NQQ) {
            int j = i - NPP;
            const float* q = part + 786432;
            float sre = 0, sim = 0;
            #pragma unroll
            for (int ks = 0; ks < 6; ++ks) {
                sre += q[ks*294912 + j];
                sim += q[ks*294912 + 147456 + j];
            }
            int r = j / NQ, c = j - r*NQ;
            float d = (r == c) ? mu : 0.0f;
            sQ += fabsf(d - sre) + fabsf(sim);
        } else {
            int j = i - (NPP+NQQ);
            const float* pq = part + 786432 + 1769472;
            float sre = 0, sim = 0;
            #pragma unroll
            for (int ks = 0; ks < 6; ++ks) {
                sre += pq[ks*196608 + j];
                sim += pq[ks*196608 + 98304 + j];
            }
            sPQ += fabsf(sre) + fabsf(sim);
        }
    }
    __shared__ float sm[8];
    float a1 = blockSum(sP, sm);
    float a2 = blockSum(sQ, sm);
    float a3 = blockSum(sPQ, sm);
    if (threadIdx.x == 0) {
        atomicAdd(&acc[5], a1);
        atomicAdd(&acc[6], a2);
        atomicAdd(&acc[7], a3);
    }
}

// ---------------- final combine ----------------
__global__ void k_final(const float* __restrict__ acc, float* __restrict__ out) {
    if (threadIdx.x == 0 && blockIdx.x == 0) {
        float N1 = acc[2];
        out[0] = W_FR*acc[4]/N1
               + W_FP*acc[5]/(float)(NP*NP)
               + W_FQ*acc[6]/(float)(NQ*NQ)
               + W_FO*acc[7]/(float)(NP*NQ);
    }
}

extern "C" void kernel_launch(void* const* d_in, const int* in_sizes, int n_in,
                              void* d_out, int out_size, void* d_ws, size_t ws_size,
                              hipStream_t stream) {
    const float* edge_vec = (const float*)d_in[0];
    const float* lattice  = (const float*)d_in[1];
    const float* apos     = (const float*)d_in[2];
    const float* hr_gt    = (const float*)d_in[3];
    const float* hr_pred  = (const float*)d_in[4];
    const float* kpt      = (const float*)d_in[5];
    const float* P_re     = (const float*)d_in[6];
    const float* P_im     = (const float*)d_in[7];
    const float* Q_re     = (const float*)d_in[8];
    const float* Q_im     = (const float*)d_in[9];
    const float* H_gt     = (const float*)d_in[10];
    const float* pred_H   = (const float*)d_in[11];
    const float* overlap  = (const float*)d_in[12];
    const float* mask     = (const float*)d_in[13];
    const int*   esrc     = (const int*)d_in[14];
    const int*   edst     = (const int*)d_in[15];
    float* out = (float*)d_out;

    float* ws   = (float*)d_ws;
    float* acc  = ws;                         // 16 f
    int*   bcnt = (int*)(ws + 16);            // 64 int
    int*   blist= (int*)(ws + 80);            // 64*128 int -> ends 8272
    float* phre = ws + 8272;                  // 1536
    float* phim = phre + E_N;                 // -> 11344
    ushort* us  = (ushort*)(ws + 16384);      // byte 65536
    ushort* Prebf  = us;                                  // 884736
    ushort* Pimbf  = Prebf  + (size_t)NP*M_DIM;
    ushort* Qrebf  = Pimbf  + (size_t)NP*M_DIM;           // 1327104
    ushort* Qimbf  = Qrebf  + (size_t)NQ*M_DIM;
    ushort* BPTPre = Qimbf  + (size_t)NQ*M_DIM;
    ushort* BPTPim = BPTPre + (size_t)NP*M_DIM;
    ushort* BPTQre = BPTPim + (size_t)NP*M_DIM;
    ushort* BPTQim = BPTQre + (size_t)NQ*M_DIM;
    unsigned* PpadR = (unsigned*)(BPTQim + (size_t)NQ*M_DIM);      // 64*640*32 uints
    unsigned* PpadI = PpadR + (size_t)64*640*32;
    unsigned* hrdG  = PpadI + (size_t)64*640*32;                   // 1536*2048 uints
    float* part = (float*)hrdG;   // aliased: k_gemm writes after k_bp consumed hrdG

    hipMemsetAsync(ws, 0, 320, stream);   // acc + bcnt

    k_phase<<<E_N/256, 256, 0, stream>>>(edge_vec, lattice, apos, kpt, esrc, edst,
                                         phre, phim, bcnt, blist);
    k_prep<<<1024, 256, 0, stream>>>((const float4*)P_re, (const float4*)P_im,
                                     (const float4*)Q_re, (const float4*)Q_im,
                                     (ushort4*)Prebf, (ushort4*)Pimbf,
                                     (ushort4*)Qrebf, (ushort4*)Qimbf);
    k_hrd<<<E_N*2048/256, 256, 0, stream>>>(hr_gt, hr_pred, hrdG);
    k_pqpad<<<64*640*32/256, 256, 0, stream>>>(Prebf, Pimbf, Qrebf, Qimbf, PpadR, PpadI);
    k_red1<<<1024, 256, 0, stream>>>((const float4*)H_gt, (const float4*)pred_H,
                                     (const float4*)overlap, (const float4*)mask, acc);
    k_bp<<<NATOMS*10, 256, 0, stream>>>(hrdG, PpadR, PpadI, phre, phim, bcnt, blist,
                                        BPTPre, BPTPim, BPTQre, BPTQim);
    k_gemm<<<456, 256, 0, stream>>>(Prebf, Pimbf, Qrebf, Qimbf,
                                    BPTPre, BPTPim, BPTQre, BPTQim, part);
    k_mu<<<1, 512, 0, stream>>>(part, acc);
    k_loss_hr<<<1024, 256, 0, stream>>>((const float4*)H_gt, (const float4*)pred_H,
                                        (const float4*)overlap, acc);
    k_loss_mats<<<256, 256, 0, stream>>>(part, acc);
    k_final<<<1, 1, 0, stream>>>(acc, out);
}

// Round 5
// 308.188 us; speedup vs baseline: 3.1517x; 1.0976x over previous
//
#include <hip/hip_runtime.h>
#include <math.h>

#define E_N    1536
#define NATOMS 64
#define M_DIM  3456          // 54*64
#define NP     256
#define NQ     384
#define HRSZ   2916          // 54*54

#define W_FP 0.0002f
#define W_FQ 0.0001f
#define W_FO 0.00015f
#define W_FR (1.0f - W_FP - W_FQ - W_FO)

// k_pre block ranges
#define B_HRD  3072          // 1536*512/256
#define B_RED  1094          // ceil(1119744/1024)
#define B_PQ   1280          // 64*640*8/256
#define B_PREP 1080          // 1105920/1024
#define B_PH   6
#define B_TOT  (B_HRD + B_RED + B_PQ + B_PREP + B_PH)

// k_loss block ranges
#define B_LHR  1094

typedef __attribute__((ext_vector_type(8))) short short8;
typedef __attribute__((ext_vector_type(4))) float f32x4;

__device__ __forceinline__ unsigned pk_bf16(float a, float b) {
    unsigned r;
    asm volatile("v_cvt_pk_bf16_f32 %0, %1, %2" : "=v"(r) : "v"(a), "v"(b));
    return r;
}
__device__ __forceinline__ unsigned short f2bf(float x) {
    unsigned u = __builtin_bit_cast(unsigned, x);
    unsigned r = (u + 0x7fffu + ((u >> 16) & 1u)) >> 16;
    return (unsigned short)r;
}

__device__ __forceinline__ void gload_lds16(const void* g, void* l) {
    __builtin_amdgcn_global_load_lds(
        (const __attribute__((address_space(1))) unsigned int*)g,
        (__attribute__((address_space(3))) unsigned int*)l, 16, 0, 0);
}

__device__ __forceinline__ float blockSum(float v, float* sm) {
    v += __shfl_down(v, 32); v += __shfl_down(v, 16); v += __shfl_down(v, 8);
    v += __shfl_down(v, 4);  v += __shfl_down(v, 2);  v += __shfl_down(v, 1);
    __syncthreads();
    if ((threadIdx.x & 63) == 0) sm[threadIdx.x >> 6] = v;
    __syncthreads();
    float r = 0.0f;
    if (threadIdx.x == 0) {
        int nw = blockDim.x >> 6;
        for (int i = 0; i < nw; ++i) r += sm[i];
    }
    return r;
}

// ================= k_pre: fused independent precompute =================
// blocks [0,B_HRD):              hrd = bf16(hr_pred-hr_gt), padded 64x64, swizzled
// blocks [B_HRD, +B_RED):        red1 sums (n1 num, ov^2, mask) with ILP4
// blocks [.., +B_PQ):            P/Q padded panels (from fp32 directly)
// blocks [.., +B_PREP):          P/Q flat bf16 (ILP4)
// blocks [.., +B_PH):            phase + edge buckets
__global__ __launch_bounds__(256) void k_pre(
        const float* __restrict__ edge_vec, const float* __restrict__ lat,
        const float* __restrict__ apos, const float* __restrict__ kpt,
        const int* __restrict__ esrc, const int* __restrict__ edst,
        const float* __restrict__ hr_gt, const float* __restrict__ hr_pred,
        const float* __restrict__ P_re, const float* __restrict__ P_im,
        const float* __restrict__ Q_re, const float* __restrict__ Q_im,
        const float4* __restrict__ Hg, const float4* __restrict__ Hp,
        const float4* __restrict__ ov, const float4* __restrict__ mk,
        float* __restrict__ phre, float* __restrict__ phim,
        int* __restrict__ bcnt, int* __restrict__ blist,
        unsigned* __restrict__ hrdG,
        unsigned* __restrict__ PpadR, unsigned* __restrict__ PpadI,
        ushort4* __restrict__ Prebf, ushort4* __restrict__ Pimbf,
        ushort4* __restrict__ Qrebf, ushort4* __restrict__ Qimbf,
        float* __restrict__ acc) {
    __shared__ float sm[8];
    int bid = blockIdx.x;
    int tid = threadIdx.x;

    if (bid < B_HRD) {
        // ---- hrd quads ----
        int idx = bid*256 + tid;          // 786432 = 1536*512
        int e = idx >> 9;
        int p = idx & 511;
        int i = p >> 3, q = p & 7;
        unsigned outv[4] = {0,0,0,0};
        if (i < 54 && q < 7) {
            const float* g = hr_gt  + (size_t)e*HRSZ + i*54;
            const float* h = hr_pred + (size_t)e*HRSZ + i*54;
            #pragma unroll
            for (int u = 0; u < 4; ++u) {
                int j2 = q*4 + u;
                if (j2 < 27) {
                    float2 gg = *(const float2*)(g + 2*j2);
                    float2 hh = *(const float2*)(h + 2*j2);
                    outv[u] = pk_bf16(hh.x - gg.x, hh.y - gg.y);
                }
            }
        }
        *(uint4*)(hrdG + (size_t)e*2048 + i*32 + ((q ^ (i & 7)) << 2)) =
            make_uint4(outv[0], outv[1], outv[2], outv[3]);
    } else if (bid < B_HRD + B_RED) {
        // ---- red1, ILP4 ----
        const int N4 = E_N*HRSZ/4;        // 1119744
        int base = (bid - B_HRD)*1024 + tid;
        float4 hg[4], hp[4], o[4], m[4];
        #pragma unroll
        for (int u = 0; u < 4; ++u) {
            int i = base + u*256;
            if (i < N4) { hg[u]=Hg[i]; hp[u]=Hp[i]; o[u]=ov[i]; m[u]=mk[i]; }
            else { hg[u]=float4{0,0,0,0}; hp[u]=hg[u]; o[u]=hg[u]; m[u]=hg[u]; }
        }
        float s0 = 0, s1 = 0, s2 = 0;
        #pragma unroll
        for (int u = 0; u < 4; ++u) {
            s0 += (hp[u].x-hg[u].x)*o[u].x + (hp[u].y-hg[u].y)*o[u].y
                + (hp[u].z-hg[u].z)*o[u].z + (hp[u].w-hg[u].w)*o[u].w;
            s1 += o[u].x*o[u].x + o[u].y*o[u].y + o[u].z*o[u].z + o[u].w*o[u].w;
            s2 += m[u].x + m[u].y + m[u].z + m[u].w;
        }
        float r0 = blockSum(s0, sm);
        float r1 = blockSum(s1, sm);
        float r2 = blockSum(s2, sm);
        if (tid == 0) {
            atomicAdd(&acc[0], r0);
            atomicAdd(&acc[1], r1);
            atomicAdd(&acc[2], r2);
        }
    } else if (bid < B_HRD + B_RED + B_PQ) {
        // ---- pqpad quads (fp32 -> padded swizzled bf16 panels) ----
        int idx = (bid - B_HRD - B_RED)*256 + tid;   // 327680 = 64*640*8
        int q = idx & 7;
        int r = idx >> 3;
        int c = r % 640;
        int dst = r / 640;
        const float* sre = (c < NP) ? (P_re + (size_t)c*M_DIM) : (Q_re + (size_t)(c-NP)*M_DIM);
        const float* sim = (c < NP) ? (P_im + (size_t)c*M_DIM) : (Q_im + (size_t)(c-NP)*M_DIM);
        unsigned vr[4] = {0,0,0,0}, vi[4] = {0,0,0,0};
        if (q < 7) {
            #pragma unroll
            for (int u = 0; u < 4; ++u) {
                int j2 = q*4 + u;
                if (j2 < 27) {
                    int o = dst*54 + 2*j2;
                    float2 fr = *(const float2*)(sre + o);
                    float2 fi = *(const float2*)(sim + o);
                    vr[u] = pk_bf16(fr.x, fr.y);
                    vi[u] = pk_bf16(fi.x, fi.y);
                }
            }
        }
        int loc = (dst*640 + c)*32 + ((q ^ (c & 7)) << 2);
        *(uint4*)(PpadR + loc) = make_uint4(vr[0], vr[1], vr[2], vr[3]);
        *(uint4*)(PpadI + loc) = make_uint4(vi[0], vi[1], vi[2], vi[3]);
    } else if (bid < B_HRD + B_RED + B_PQ + B_PREP) {
        // ---- prep flat bf16, ILP4 (exact fit: 1080*1024 = 1105920) ----
        const int NP4 = NP*M_DIM/4;       // 221184
        const int NQ4 = NQ*M_DIM/4;       // 331776
        int base = (bid - B_HRD - B_RED - B_PQ)*1024 + tid;
        #pragma unroll
        for (int u = 0; u < 4; ++u) {
            int i = base + u*256;
            const float4* src; ushort4* dst; int o;
            if (i < NP4)            { src = (const float4*)P_re; dst = Prebf; o = i; }
            else if (i < 2*NP4)     { src = (const float4*)P_im; dst = Pimbf; o = i - NP4; }
            else if (i < 2*NP4+NQ4) { src = (const float4*)Q_re; dst = Qrebf; o = i - 2*NP4; }
            else                    { src = (const float4*)Q_im; dst = Qimbf; o = i - 2*NP4 - NQ4; }
            float4 v = src[o];
            ushort4 uu;
            uu.x = f2bf(v.x); uu.y = f2bf(v.y); uu.z = f2bf(v.z); uu.w = f2bf(v.w);
            dst[o] = uu;
        }
    } else {
        // ---- phase + buckets ----
        int e = (bid - B_HRD - B_RED - B_PQ - B_PREP)*256 + tid;
        if (e >= E_N) return;
        float a00 = lat[0], a01 = lat[3], a02 = lat[6];
        float a10 = lat[1], a11 = lat[4], a12 = lat[7];
        float a20 = lat[2], a21 = lat[5], a22 = lat[8];
        float c00 = a11*a22 - a12*a21;
        float c01 = a12*a20 - a10*a22;
        float c02 = a10*a21 - a11*a20;
        float det = a00*c00 + a01*c01 + a02*c02;
        float id  = 1.0f / det;
        float i00 = c00*id;
        float i01 = (a02*a21 - a01*a22)*id;
        float i02 = (a01*a12 - a02*a11)*id;
        float i10 = c01*id;
        float i11 = (a00*a22 - a02*a20)*id;
        float i12 = (a02*a10 - a00*a12)*id;
        float i20 = c02*id;
        float i21 = (a01*a20 - a00*a21)*id;
        float i22 = (a00*a11 - a01*a10)*id;
        int s = esrc[e], d = edst[e];
        float r0 = edge_vec[e*3+0] - (apos[d*3+0] - apos[s*3+0]);
        float r1 = edge_vec[e*3+1] - (apos[d*3+1] - apos[s*3+1]);
        float r2 = edge_vec[e*3+2] - (apos[d*3+2] - apos[s*3+2]);
        float t0 = roundf(i00*r0 + i01*r1 + i02*r2);
        float t1 = roundf(i10*r0 + i11*r1 + i12*r2);
        float t2 = roundf(i20*r0 + i21*r1 + i22*r2);
        float ph = t0*kpt[0] + t1*kpt[1] + t2*kpt[2];
        float ang = 6.28318530717958647692f * ph;
        phre[e] = cosf(ang);
        phim[e] = sinf(ang);
        int p = atomicAdd(&bcnt[s], 1);
        if (p < 128) blist[s*128 + p] = (e << 6) | d;
    }
}

// ================= k_bp: BP^T via per-edge MFMA, double-buffered =================
// grid 640 = 64 atoms x 10 col-tiles; 256 thr = 4 waves (2x2 of 32x32 output)
__global__ __launch_bounds__(256) void k_bp(
        const unsigned* __restrict__ hrdG,
        const unsigned* __restrict__ PpadR, const unsigned* __restrict__ PpadI,
        const float* __restrict__ phre, const float* __restrict__ phim,
        const int* __restrict__ bcnt, const int* __restrict__ blist,
        ushort* __restrict__ BPTPre, ushort* __restrict__ BPTPim,
        ushort* __restrict__ BPTQre, ushort* __restrict__ BPTQim) {
    __shared__ ushort lds[2][12288];    // 48 KB: 2 x {hrd, PpadR, PpadI}
    __shared__ int elist[128];
    __shared__ float phs[2][128];

    int tid = threadIdx.x;
    int a   = blockIdx.x / 10;
    int t   = blockIdx.x - a*10;
    ushort *Or, *Oi; int col0;
    if (t < 4) { Or = BPTPre; Oi = BPTPim; col0 = t*64; }
    else       { Or = BPTQre; Oi = BPTQim; col0 = (t-4)*64; }

    int ne = bcnt[a]; if (ne > 128) ne = 128;
    for (int k = tid; k < ne; k += 256) {
        int v = blist[a*128 + k];
        elist[k] = v;
        phs[0][k] = phre[v >> 6];
        phs[1][k] = phim[v >> 6];
    }
    __syncthreads();

    int w = tid >> 6, l = tid & 63;
    int wr0 = (w >> 1)*32, wc0 = (w & 1)*32;
    int lr = l & 15, kq = l >> 4, lk4 = (l >> 4)*4;

    f32x4 accRe[2][2] = {}, accIm[2][2] = {};

    // per wave: exactly 6 global_load_lds ops per edge (nothing else touches vmcnt in-loop)
    #define ISSUE(nn, bb) do {                                                     \
        int v_ = elist[(nn)];                                                      \
        int ee_ = v_ >> 6, dst_ = v_ & 63;                                         \
        const ushort* g0_ = (const ushort*)(hrdG + (size_t)ee_*2048);              \
        const ushort* g1_ = (const ushort*)(PpadR + ((size_t)dst_*640 + t*64)*32); \
        const ushort* g2_ = (const ushort*)(PpadI + ((size_t)dst_*640 + t*64)*32); \
        ushort* lb_ = &lds[(bb)][0];                                               \
        _Pragma("unroll")                                                          \
        for (int j_ = 0; j_ < 6; ++j_) {                                           \
            int jj_ = w + j_*4;                                                    \
            int arr_ = jj_ >> 3, ch_ = jj_ & 7;                                    \
            const ushort* gb_ = (arr_ == 0) ? g0_ : (arr_ == 1) ? g1_ : g2_;       \
            gload_lds16(gb_ + ch_*512 + l*8, (void*)(lb_ + arr_*4096 + ch_*512));  \
        }                                                                          \
    } while (0)

    if (ne > 0) ISSUE(0, 0);
    for (int n = 0; n < ne; ++n) {
        int cur = n & 1;
        if (n + 1 < ne) {
            ISSUE(n+1, 1-cur);
            asm volatile("s_waitcnt vmcnt(6)" ::: "memory");
        } else {
            asm volatile("s_waitcnt vmcnt(0)" ::: "memory");
        }
        __syncthreads();
        float phr = phs[0][n], phi_ = phs[1][n];
        const ushort* A  = &lds[cur][0];
        const ushort* BR = A + 4096;
        const ushort* BI = A + 8192;
        short8 a0[2], a1[2], br0[2], br1[2], bi0[2], bi1[2];
        #pragma unroll
        for (int mr = 0; mr < 2; ++mr) {
            int r = wr0 + mr*16 + lr;
            a0[mr] = *(const short8*)(A + r*64 + ((kq     ^ (r & 7))<<3));
            a1[mr] = *(const short8*)(A + r*64 + (((4+kq) ^ (r & 7))<<3));
        }
        #pragma unroll
        for (int nc = 0; nc < 2; ++nc) {
            int c = wc0 + nc*16 + lr;
            br0[nc] = *(const short8*)(BR + c*64 + ((kq     ^ (c & 7))<<3));
            br1[nc] = *(const short8*)(BR + c*64 + (((4+kq) ^ (c & 7))<<3));
            bi0[nc] = *(const short8*)(BI + c*64 + ((kq     ^ (c & 7))<<3));
            bi1[nc] = *(const short8*)(BI + c*64 + (((4+kq) ^ (c & 7))<<3));
        }
        f32x4 z = {0.0f, 0.0f, 0.0f, 0.0f};
        f32x4 t1[2][2], t2[2][2];
        #pragma unroll
        for (int mr = 0; mr < 2; ++mr)
            #pragma unroll
            for (int nc = 0; nc < 2; ++nc) {
                t1[mr][nc] = __builtin_amdgcn_mfma_f32_16x16x32_bf16(a0[mr], br0[nc], z, 0, 0, 0);
                t1[mr][nc] = __builtin_amdgcn_mfma_f32_16x16x32_bf16(a1[mr], br1[nc], t1[mr][nc], 0, 0, 0);
                t2[mr][nc] = __builtin_amdgcn_mfma_f32_16x16x32_bf16(a0[mr], bi0[nc], z, 0, 0, 0);
                t2[mr][nc] = __builtin_amdgcn_mfma_f32_16x16x32_bf16(a1[mr], bi1[nc], t2[mr][nc], 0, 0, 0);
            }
        #pragma unroll
        for (int mr = 0; mr < 2; ++mr)
            #pragma unroll
            for (int nc = 0; nc < 2; ++nc)
                #pragma unroll
                for (int q = 0; q < 4; ++q) {
                    accRe[mr][nc][q] += phr*t1[mr][nc][q] - phi_*t2[mr][nc][q];
                    accIm[mr][nc][q] += phr*t2[mr][nc][q] + phi_*t1[mr][nc][q];
                }
        __syncthreads();
    }
    #undef ISSUE

    #pragma unroll
    for (int mr = 0; mr < 2; ++mr)
        #pragma unroll
        for (int nc = 0; nc < 2; ++nc) {
            int ib = wr0 + mr*16 + lk4;
            if (ib < 54) {
                int cg = col0 + wc0 + nc*16 + lr;
                size_t base = (size_t)cg*M_DIM + (size_t)a*54 + ib;
                *(unsigned*)(Or + base) = pk_bf16(accRe[mr][nc][0], accRe[mr][nc][1]);
                *(unsigned*)(Oi + base) = pk_bf16(accIm[mr][nc][0], accIm[mr][nc][1]);
                if (ib + 2 < 54) {
                    *(unsigned*)(Or + base + 2) = pk_bf16(accRe[mr][nc][2], accRe[mr][nc][3]);
                    *(unsigned*)(Oi + base + 2) = pk_bf16(accIm[mr][nc][2], accIm[mr][nc][3]);
                }
            }
        }
}

// ================= k_gemm: bf16 MFMA, 64x64 tile, K-split 6, partial slices =================
#define GPAD 40
__global__ __launch_bounds__(256) void k_gemm(
        const ushort* __restrict__ Prebf, const ushort* __restrict__ Pimbf,
        const ushort* __restrict__ Qrebf, const ushort* __restrict__ Qimbf,
        const ushort* __restrict__ BPTPre, const ushort* __restrict__ BPTPim,
        const ushort* __restrict__ BPTQre, const ushort* __restrict__ BPTQim,
        float* __restrict__ part) {
    __shared__ ushort Ar[64*GPAD], Ai[64*GPAD], Br_[64*GPAD], Bi_[64*GPAD];
    int tid = threadIdx.x;
    int bid = blockIdx.x;
    int t = bid / 6, ks = bid - t*6;
    const ushort *Ag, *Aig, *Bg, *Big; float *Cre, *Cim; int NC, r0, c0;
    if (t < 16) {
        Ag = Prebf; Aig = Pimbf; Bg = BPTPre; Big = BPTPim;
        NC = NP; r0 = (t & 3)*64; c0 = (t >> 2)*64;
        Cre = part + (size_t)ks*2*65536; Cim = Cre + 65536;
    } else if (t < 52) {
        int u = t - 16;
        Ag = Qrebf; Aig = Qimbf; Bg = BPTQre; Big = BPTQim;
        NC = NQ; r0 = (u % 6)*64; c0 = (u / 6)*64;
        Cre = part + 786432 + (size_t)ks*2*147456; Cim = Cre + 147456;
    } else {
        int u = t - 52;
        Ag = Prebf; Aig = Pimbf; Bg = BPTQre; Big = BPTQim;
        NC = NQ; r0 = (u & 3)*64; c0 = (u >> 2)*64;
        Cre = part + 786432 + 1769472 + (size_t)ks*2*98304; Cim = Cre + 98304;
    }
    int k0 = ks * 576;
    int srow = tid >> 2, skq = (tid & 3) * 8;
    int w = tid >> 6, l = tid & 63;
    int wr0 = (w >> 1)*32, wc0 = (w & 1)*32;
    int lr = l & 15, lk = (l >> 4)*8, lk4 = (l >> 4)*4;

    const ushort* pa  = Ag  + (size_t)(r0+srow)*M_DIM + k0 + skq;
    const ushort* pai = Aig + (size_t)(r0+srow)*M_DIM + k0 + skq;
    const ushort* pb  = Bg  + (size_t)(c0+srow)*M_DIM + k0 + skq;
    const ushort* pbi = Big + (size_t)(c0+srow)*M_DIM + k0 + skq;

    short8 ra = *(const short8*)pa, rai = *(const short8*)pai;
    short8 rb = *(const short8*)pb, rbi = *(const short8*)pbi;

    f32x4 aRe[2][2] = {}, aIA[2][2] = {}, aIB[2][2] = {};
    for (int s = 0; s < 18; ++s) {
        __syncthreads();
        *(short8*)(Ar  + srow*GPAD + skq) = ra;
        *(short8*)(Ai  + srow*GPAD + skq) = rai;
        *(short8*)(Br_ + srow*GPAD + skq) = rb;
        *(short8*)(Bi_ + srow*GPAD + skq) = rbi;
        __syncthreads();
        if (s < 17) {
            int o = (s+1)*32;
            ra  = *(const short8*)(pa  + o);
            rai = *(const short8*)(pai + o);
            rb  = *(const short8*)(pb  + o);
            rbi = *(const short8*)(pbi + o);
        }
        short8 fa[2], fn[2], fb[2], fi[2];
        #pragma unroll
        for (int mr = 0; mr < 2; ++mr) {
            int r = wr0 + mr*16 + lr;
            fa[mr] = *(const short8*)(Ar + r*GPAD + lk);
            fn[mr] = *(const short8*)(Ai + r*GPAD + lk);
        }
        #pragma unroll
        for (int nc = 0; nc < 2; ++nc) {
            int c = wc0 + nc*16 + lr;
            fb[nc] = *(const short8*)(Br_ + c*GPAD + lk);
            fi[nc] = *(const short8*)(Bi_ + c*GPAD + lk);
        }
        #pragma unroll
        for (int mr = 0; mr < 2; ++mr)
            #pragma unroll
            for (int nc = 0; nc < 2; ++nc) {
                aRe[mr][nc] = __builtin_amdgcn_mfma_f32_16x16x32_bf16(fa[mr], fb[nc], aRe[mr][nc], 0, 0, 0);
                aRe[mr][nc] = __builtin_amdgcn_mfma_f32_16x16x32_bf16(fn[mr], fi[nc], aRe[mr][nc], 0, 0, 0);
                aIA[mr][nc] = __builtin_amdgcn_mfma_f32_16x16x32_bf16(fa[mr], fi[nc], aIA[mr][nc], 0, 0, 0);
                aIB[mr][nc] = __builtin_amdgcn_mfma_f32_16x16x32_bf16(fn[mr], fb[nc], aIB[mr][nc], 0, 0, 0);
            }
    }
    #pragma unroll
    for (int mr = 0; mr < 2; ++mr)
        #pragma unroll
        for (int nc = 0; nc < 2; ++nc)
            #pragma unroll
            for (int rr = 0; rr < 4; ++rr) {
                int row = r0 + wr0 + mr*16 + lk4 + rr;
                int col = c0 + wc0 + nc*16 + lr;
                Cre[(size_t)row*NC + col] = aRe[mr][nc][rr];
                Cim[(size_t)row*NC + col] = aIA[mr][nc][rr] - aIB[mr][nc][rr];
            }
}

// ================= mu from traces (sum 6 K-partials) =================
__global__ void k_mu(const float* __restrict__ part, float* __restrict__ acc) {
    int t = threadIdx.x;  // 512
    float v1 = 0.0f, v2 = 0.0f;
    if (t < NP) {
        #pragma unroll
        for (int ks = 0; ks < 6; ++ks) v1 += part[ks*131072 + t*(NP+1)];
    }
    if (t < NQ) {
        const float* q = part + 786432;
        #pragma unroll
        for (int ks = 0; ks < 6; ++ks) v2 += q[ks*294912 + t*(NQ+1)];
    }
    __shared__ float sm[8];
    float trP = blockSum(v1, sm);
    float trQ = blockSum(v2, sm);
    if (t == 0) {
        float N1 = acc[2];
        float n1 = W_FR * acc[0] / N1;
        float d1 = W_FR * acc[1] / N1;
        float n2 = W_FP * trP / (float)(NP*NP);
        float n3 = W_FQ * trQ / (float)(NQ*NQ);
        float d2 = W_FP / (float)NP;
        float d3 = W_FQ / (float)NQ;
        acc[3] = (n1 + n2 + n3) / (d1 + d2 + d3);
    }
}

// ================= k_loss: loss_hr (ILP4) + loss_mats fused =================
__global__ __launch_bounds__(256) void k_loss(
        const float4* __restrict__ Hg, const float4* __restrict__ Hp,
        const float4* __restrict__ ov, const float* __restrict__ part,
        float* __restrict__ acc) {
    __shared__ float sm[8];
    int bid = blockIdx.x;
    int tid = threadIdx.x;
    float mu = acc[3];
    if (bid < B_LHR) {
        const int N4 = E_N*HRSZ/4;
        int base = bid*1024 + tid;
        float4 hg[4], hp[4], o[4];
        #pragma unroll
        for (int u = 0; u < 4; ++u) {
            int i = base + u*256;
            if (i < N4) { hg[u]=Hg[i]; hp[u]=Hp[i]; o[u]=ov[i]; }
            else { hg[u]=float4{0,0,0,0}; hp[u]=hg[u]; o[u]=hg[u]; }
        }
        float s = 0;
        #pragma unroll
        for (int u = 0; u < 4; ++u) {
            s += fabsf(hg[u].x + mu*o[u].x - hp[u].x) + fabsf(hg[u].y + mu*o[u].y - hp[u].y)
               + fabsf(hg[u].z + mu*o[u].z - hp[u].z) + fabsf(hg[u].w + mu*o[u].w - hp[u].w);
        }
        float r = blockSum(s, sm);
        if (tid == 0) atomicAdd(&acc[4], r);
    } else {
        const int NPP = NP*NP, NQQ = NQ*NQ, NPQ = NP*NQ;
        float sP = 0, sQ = 0, sPQ = 0;
        int stride = 256*256;
        for (int i = (bid - B_LHR)*256 + tid; i < NPP+NQQ+NPQ; i += stride) {
            if (i < NPP) {
                float sre = 0, sim = 0;
                #pragma unroll
                for (int ks = 0; ks < 6; ++ks) {
                    sre += part[ks*131072 + i];
                    sim += part[ks*131072 + 65536 + i];
                }
                int r = i >> 8, c = i & 255;
                float d = (r == c) ? mu : 0.0f;
                sP += fabsf(d - sre) + fabsf(sim);
            } else if (i < NPP+NQQ) {
                int j = i - NPP;
                const float* q = part + 786432;
                float sre = 0, sim = 0;
                #pragma unroll
                for (int ks = 0; ks < 6; ++ks) {
                    sre += q[ks*294912 + j];
                    sim += q[ks*294912 + 147456 + j];
                }
                int r = j / NQ, c = j - r*NQ;
                float d = (r == c) ? mu : 0.0f;
                sQ += fabsf(d - sre) + fabsf(sim);
            } else {
                int j = i - (NPP+NQQ);
                const float* pq = part + 786432 + 1769472;
                float sre = 0, sim = 0;
                #pragma unroll
                for (int ks = 0; ks < 6; ++ks) {
                    sre += pq[ks*196608 + j];
                    sim += pq[ks*196608 + 98304 + j];
                }
                sPQ += fabsf(sre) + fabsf(sim);
            }
        }
        float a1 = blockSum(sP, sm);
        float a2 = blockSum(sQ, sm);
        float a3 = blockSum(sPQ, sm);
        if (tid == 0) {
            atomicAdd(&acc[5], a1);
            atomicAdd(&acc[6], a2);
            atomicAdd(&acc[7], a3);
        }
    }
}

// ================= final combine =================
__global__ void k_final(const float* __restrict__ acc, float* __restrict__ out) {
    if (threadIdx.x == 0 && blockIdx.x == 0) {
        float N1 = acc[2];
        out[0] = W_FR*acc[4]/N1
               + W_FP*acc[5]/(float)(NP*NP)
               + W_FQ*acc[6]/(float)(NQ*NQ)
               + W_FO*acc[7]/(float)(NP*NQ);
    }
}

extern "C" void kernel_launch(void* const* d_in, const int* in_sizes, int n_in,
                              void* d_out, int out_size, void* d_ws, size_t ws_size,
                              hipStream_t stream) {
    const float* edge_vec = (const float*)d_in[0];
    const float* lattice  = (const float*)d_in[1];
    const float* apos     = (const float*)d_in[2];
    const float* hr_gt    = (const float*)d_in[3];
    const float* hr_pred  = (const float*)d_in[4];
    const float* kpt      = (const float*)d_in[5];
    const float* P_re     = (const float*)d_in[6];
    const float* P_im     = (const float*)d_in[7];
    const float* Q_re     = (const float*)d_in[8];
    const float* Q_im     = (const float*)d_in[9];
    const float* H_gt     = (const float*)d_in[10];
    const float* pred_H   = (const float*)d_in[11];
    const float* overlap  = (const float*)d_in[12];
    const float* mask     = (const float*)d_in[13];
    const int*   esrc     = (const int*)d_in[14];
    const int*   edst     = (const int*)d_in[15];
    float* out = (float*)d_out;

    float* ws   = (float*)d_ws;
    float* acc  = ws;                         // 16 f
    int*   bcnt = (int*)(ws + 16);            // 64 int
    int*   blist= (int*)(ws + 80);            // 64*128 int -> ends 8272
    float* phre = ws + 8272;                  // 1536
    float* phim = phre + E_N;                 // -> 11344
    ushort* us  = (ushort*)(ws + 16384);      // byte 65536
    ushort* Prebf  = us;
    ushort* Pimbf  = Prebf  + (size_t)NP*M_DIM;
    ushort* Qrebf  = Pimbf  + (size_t)NP*M_DIM;
    ushort* Qimbf  = Qrebf  + (size_t)NQ*M_DIM;
    ushort* BPTPre = Qimbf  + (size_t)NQ*M_DIM;
    ushort* BPTPim = BPTPre + (size_t)NP*M_DIM;
    ushort* BPTQre = BPTPim + (size_t)NP*M_DIM;
    ushort* BPTQim = BPTQre + (size_t)NQ*M_DIM;
    unsigned* PpadR = (unsigned*)(BPTQim + (size_t)NQ*M_DIM);      // 64*640*32 uints
    unsigned* PpadI = PpadR + (size_t)64*640*32;
    unsigned* hrdG  = PpadI + (size_t)64*640*32;                   // 1536*2048 uints
    float* part = (float*)hrdG;   // aliased: k_gemm writes after k_bp consumed hrdG

    hipMemsetAsync(ws, 0, 320, stream);   // acc + bcnt

    k_pre<<<B_TOT, 256, 0, stream>>>(edge_vec, lattice, apos, kpt, esrc, edst,
                                     hr_gt, hr_pred, P_re, P_im, Q_re, Q_im,
                                     (const float4*)H_gt, (const float4*)pred_H,
                                     (const float4*)overlap, (const float4*)mask,
                                     phre, phim, bcnt, blist,
                                     hrdG, PpadR, PpadI,
                                     (ushort4*)Prebf, (ushort4*)Pimbf,
                                     (ushort4*)Qrebf, (ushort4*)Qimbf, acc);
    k_bp<<<NATOMS*10, 256, 0, stream>>>(hrdG, PpadR, PpadI, phre, phim, bcnt, blist,
                                        BPTPre, BPTPim, BPTQre, BPTQim);
    k_gemm<<<456, 256, 0, stream>>>(Prebf, Pimbf, Qrebf, Qimbf,
                                    BPTPre, BPTPim, BPTQre, BPTQim, part);
    k_mu<<<1, 512, 0, stream>>>(part, acc);
    k_loss<<<B_LHR + 256, 256, 0, stream>>>((const float4*)H_gt, (const float4*)pred_H,
                                            (const float4*)overlap, part, acc);
    k_final<<<1, 1, 0, stream>>>(acc, out);
}